// Round 4
// baseline (339.587 us; speedup 1.0000x reference)
//
#include <hip/hip_runtime.h>
#include <hip/hip_bf16.h>
#include <cstdint>

#define B_ 4
#define S_ 2048
#define E_ 1024
#define H_ 16
#define HD_ 64
#define EPS_ 1.1920928955078125e-07f

typedef __attribute__((ext_vector_type(8))) short shortx8;
typedef __attribute__((ext_vector_type(4))) float floatx4;

// softmax scale folded into Q at prep time: Q *= 0.125*log2(e), so
// P = exp2(QK^T) directly (|logit*0.125| <= 8 by Cauchy-Schwarz, so
// p <= e^8 ~ 2981 -- safely in bf16/fp32 range; normalization divides out).
#define C1_ 0.18033688068389154f   // 0.125 * log2(e)

// ---------------------------------------------------------------------------
// Kernel 1: fused RMSNorm + RoPE for q and k, cast to bf16, transpose to
// [B,H,S,HD]. One thread per 4 consecutive elements; one 16-lane quad per
// head-vector (HD=64). RoPE pairs are intra-thread (even dl).
// Q additionally pre-scaled by C1_ (softmax scale + log2e fold).
// ---------------------------------------------------------------------------
__global__ __launch_bounds__(256) void qk_prep(
    const float* __restrict__ q, const float* __restrict__ k,
    const float* __restrict__ qw, const float* __restrict__ kw,
    __hip_bfloat16* __restrict__ qh, __hip_bfloat16* __restrict__ kh)
{
    const size_t PT = (size_t)B_ * S_ * E_ / 4;     // float4 groups per tensor
    size_t t = (size_t)blockIdx.x * 256 + threadIdx.x;
    const bool is_k = (t >= PT);
    if (is_k) t -= PT;

    const int row = (int)(t >> 8);        // (b,s) row: E/4 = 256 groups
    const int b   = row / S_;
    const int s   = row % S_;
    const int grp = (int)(t & 255);
    const int h   = grp >> 4;             // head
    const int dl  = (grp & 15) * 4;       // dim offset within head (mult of 4)

    const float* __restrict__ src = is_k ? k : q;
    const float* __restrict__ w   = is_k ? kw : qw;
    __hip_bfloat16* __restrict__ dst = is_k ? kh : qh;

    const float4 x  = ((const float4*)src)[t];
    const float4 wv = ((const float4*)w)[grp & 15];

    // RMS over the head-vector: 16 threads (one quad) hold it
    float ss = x.x * x.x + x.y * x.y + x.z * x.z + x.w * x.w;
#pragma unroll
    for (int m = 1; m < 16; m <<= 1) ss += __shfl_xor(ss, m);
    float r = rsqrtf(ss * (1.0f / HD_) + EPS_);
    if (!is_k) r *= C1_;                  // fold softmax scale into Q

    const float xn0 = x.x * r * wv.x;
    const float xn1 = x.y * r * wv.y;
    const float xn2 = x.z * r * wv.z;
    const float xn3 = x.w * r * wv.w;

    // RoPE: pairs (dl,dl+1) and (dl+2,dl+3); i = pair index
    const float L2I = 0.41524101186092029f;   // log2(10000)/32
    const int   i0  = dl >> 1;
    const float f0  = (float)s * exp2f(-(float)i0 * L2I);
    const float f1  = (float)s * exp2f(-(float)(i0 + 1) * L2I);
    const float c0 = cosf(f0), sn0 = sinf(f0);
    const float c1 = cosf(f1), sn1 = sinf(f1);

    __hip_bfloat16 pk[4];
    pk[0] = __float2bfloat16(xn0 * c0 - xn1 * sn0);
    pk[1] = __float2bfloat16(xn0 * sn0 + xn1 * c0);
    pk[2] = __float2bfloat16(xn2 * c1 - xn3 * sn1);
    pk[3] = __float2bfloat16(xn2 * sn1 + xn3 * c1);
    *(ushort4*)(dst + ((size_t)((b * H_ + h) * S_ + s)) * HD_ + dl) =
        *(const ushort4*)pk;
}

// ---------------------------------------------------------------------------
// Kernel 2: transpose V to [B,H,HD,S] bf16 via LDS 64x64 tile.
// ---------------------------------------------------------------------------
__global__ __launch_bounds__(256) void v_trans(
    const float* __restrict__ v, __hip_bfloat16* __restrict__ vt)
{
    __shared__ __hip_bfloat16 tile[64][72];

    const int bh = blockIdx.y;
    const int s0 = blockIdx.x * 64;
    const int b  = bh >> 4, h = bh & 15;
    const int t  = threadIdx.x;

    {
        const int sl = t >> 2;
        const int d0 = (t & 3) * 16;
        const float* __restrict__ src =
            v + ((size_t)(b * S_ + s0 + sl)) * E_ + h * HD_ + d0;
        float4 f0 = ((const float4*)src)[0];
        float4 f1 = ((const float4*)src)[1];
        float4 f2 = ((const float4*)src)[2];
        float4 f3 = ((const float4*)src)[3];
        float vals[16] = {f0.x,f0.y,f0.z,f0.w, f1.x,f1.y,f1.z,f1.w,
                          f2.x,f2.y,f2.z,f2.w, f3.x,f3.y,f3.z,f3.w};
#pragma unroll
        for (int j = 0; j < 16; ++j)
            tile[d0 + j][sl] = __float2bfloat16(vals[j]);
    }
    __syncthreads();
    {
        const int d  = t >> 2;
        const int sg = (t & 3) * 16;
        __hip_bfloat16* __restrict__ dst =
            vt + ((size_t)(bh * HD_ + d)) * S_ + s0 + sg;
        ((uint4*)dst)[0] = *(const uint4*)&tile[d][sg];
        ((uint4*)dst)[1] = *(const uint4*)&tile[d][sg + 8];
    }
}

// ---------------------------------------------------------------------------
// Kernel 3: proj_w fp32 -> bf16
// ---------------------------------------------------------------------------
__global__ __launch_bounds__(256) void wconv(
    const float* __restrict__ w, __hip_bfloat16* __restrict__ wb)
{
    const int i = blockIdx.x * 256 + threadIdx.x;
    float4 f = ((const float4*)w)[i];
    wb[4 * i + 0] = __float2bfloat16(f.x);
    wb[4 * i + 1] = __float2bfloat16(f.y);
    wb[4 * i + 2] = __float2bfloat16(f.z);
    wb[4 * i + 3] = __float2bfloat16(f.w);
}

// ---------------------------------------------------------------------------
// Kernel 4: flash attention, fixed-scale softmax (scale pre-folded into Q).
// Block = 4 waves; each wave owns 32 Q rows (two 16-row halves). BM=128.
// K tiles of 64. Row-sums l via MFMA ones-row d-tile (constant, frags hoisted
// out of the K-loop). K/V fragment LDS reads hoisted out of the mh loop
// (read once per tile, reused by both halves): LDS traffic 46->26 KB/tile/wave.
// MFMA 16x16x32 bf16 layouts (m89/m91/m120 verified):
//   A[m=lane&15][k=quad*8+j]  B[k=quad*8+j][n=lane&15]  C[row=quad*4+r][col=lane&15]
// ---------------------------------------------------------------------------
__global__ __launch_bounds__(256) void attn(
    const __hip_bfloat16* __restrict__ qh, const __hip_bfloat16* __restrict__ kh,
    const __hip_bfloat16* __restrict__ vt, __hip_bfloat16* __restrict__ ctx)
{
    __shared__ __hip_bfloat16 Kt[64][72];        // [key][d]
    __shared__ __hip_bfloat16 Vt[80][72];        // [d][key]; rows 64..79: ones-tile
    __shared__ __hip_bfloat16 Pl[4][16][72];     // per-wave P round-trip

    const int bh   = blockIdx.y;
    const int q0   = blockIdx.x * 128;
    const int tid  = threadIdx.x;
    const int wv   = tid >> 6;
    const int lane = tid & 63;
    const int l16  = lane & 15;
    const int quad = lane >> 4;
    const int b    = bh >> 4, h = bh & 15;

    // init ones-tile rows of Vt (row 64 = 1.0, rows 65..79 = 0)
    for (int idx = tid; idx < 16 * 72; idx += 256) {
        const int rr = idx / 72, cc = idx % 72;
        Vt[64 + rr][cc] = (rr == 0) ? __float2bfloat16(1.0f)
                                    : __float2bfloat16(0.0f);
    }

    // Q fragments: two 16-row halves
    shortx8 aq[2][2];
#pragma unroll
    for (int mh = 0; mh < 2; ++mh) {
        const __hip_bfloat16* qbase =
            qh + ((size_t)bh * S_ + q0 + wv * 32 + mh * 16 + l16) * HD_;
        aq[mh][0] = *(const shortx8*)(qbase + quad * 8);
        aq[mh][1] = *(const shortx8*)(qbase + 32 + quad * 8);
    }

    __syncthreads();   // ones-tile visible to all waves
    // constant ones-frags: hoisted out of the K-loop entirely
    const shortx8 bo0 = *(const shortx8*)&Vt[64 + l16][quad * 8];
    const shortx8 bo1 = *(const shortx8*)&Vt[64 + l16][32 + quad * 8];

    floatx4 O[2][4] = {};     // [m-half][d-tile]
    floatx4 O5[2]   = {};     // row-sum accumulator (ones-tile)

    const __hip_bfloat16* __restrict__ kbase = kh + (size_t)bh * S_ * HD_;
    const __hip_bfloat16* __restrict__ vbase = vt + (size_t)bh * HD_ * S_;

    const int sr = tid >> 2;
    const int sc = (tid & 3) * 16;

    for (int kt = 0; kt < S_ / 64; ++kt) {
        const __hip_bfloat16* kp = kbase + ((size_t)(kt * 64 + sr)) * HD_ + sc;
        uint4 kv0 = *(const uint4*)kp;
        uint4 kv1 = *(const uint4*)(kp + 8);
        const __hip_bfloat16* vp = vbase + (size_t)sr * S_ + kt * 64 + sc;
        uint4 vv0 = *(const uint4*)vp;
        uint4 vv1 = *(const uint4*)(vp + 8);
        *(uint4*)&Kt[sr][sc]     = kv0;
        *(uint4*)&Kt[sr][sc + 8] = kv1;
        *(uint4*)&Vt[sr][sc]     = vv0;
        *(uint4*)&Vt[sr][sc + 8] = vv1;
        __syncthreads();

        // ---- hoisted fragment reads: once per tile, reused by both mh ----
        shortx8 kb[4][2], vb[4][2];
#pragma unroll
        for (int nt = 0; nt < 4; ++nt) {
            kb[nt][0] = *(const shortx8*)&Kt[nt * 16 + l16][quad * 8];
            kb[nt][1] = *(const shortx8*)&Kt[nt * 16 + l16][32 + quad * 8];
            vb[nt][0] = *(const shortx8*)&Vt[nt * 16 + l16][quad * 8];
            vb[nt][1] = *(const shortx8*)&Vt[nt * 16 + l16][32 + quad * 8];
        }

#pragma unroll
        for (int mh = 0; mh < 2; ++mh) {
            // ---- QK^T: 16 q-rows x 64 keys ----
            floatx4 s4[4];
#pragma unroll
            for (int nt = 0; nt < 4; ++nt) {
                floatx4 c = {0.f, 0.f, 0.f, 0.f};
                c = __builtin_amdgcn_mfma_f32_16x16x32_bf16(aq[mh][0], kb[nt][0], c, 0, 0, 0);
                c = __builtin_amdgcn_mfma_f32_16x16x32_bf16(aq[mh][1], kb[nt][1], c, 0, 0, 0);
                s4[nt] = c;
            }

            // ---- softmax numerator p = exp2(s) + pack to LDS ----
            asm volatile("s_waitcnt lgkmcnt(0)" ::: "memory");
#pragma unroll
            for (int nt = 0; nt < 4; ++nt)
#pragma unroll
                for (int r = 0; r < 4; ++r) {
                    const float p = exp2f(s4[nt][r]);
                    Pl[wv][quad * 4 + r][nt * 16 + l16] = __float2bfloat16(p);
                }
            asm volatile("s_waitcnt lgkmcnt(0)" ::: "memory");
            const shortx8 ap0 = *(const shortx8*)&Pl[wv][l16][quad * 8];
            const shortx8 ap1 = *(const shortx8*)&Pl[wv][l16][32 + quad * 8];

            // ---- PV: O += P(16x64) * V(64x64); l via ones-tile ----
#pragma unroll
            for (int dt = 0; dt < 4; ++dt) {
                O[mh][dt] = __builtin_amdgcn_mfma_f32_16x16x32_bf16(ap0, vb[dt][0], O[mh][dt], 0, 0, 0);
                O[mh][dt] = __builtin_amdgcn_mfma_f32_16x16x32_bf16(ap1, vb[dt][1], O[mh][dt], 0, 0, 0);
            }
            O5[mh] = __builtin_amdgcn_mfma_f32_16x16x32_bf16(ap0, bo0, O5[mh], 0, 0, 0);
            O5[mh] = __builtin_amdgcn_mfma_f32_16x16x32_bf16(ap1, bo1, O5[mh], 0, 0, 0);
        }
        __syncthreads();
    }

    // ---- epilogue: normalize (l sits at col 0 of ones-tile = lane quad*16) ----
#pragma unroll
    for (int mh = 0; mh < 2; ++mh)
#pragma unroll
        for (int r = 0; r < 4; ++r) {
            const float lv  = __shfl(O5[mh][r], quad << 4);
            const float inv = 1.0f / lv;
            const int s = q0 + wv * 32 + mh * 16 + quad * 4 + r;
#pragma unroll
            for (int dt = 0; dt < 4; ++dt) {
                const int d = dt * 16 + l16;
                ctx[((size_t)(b * S_ + s)) * E_ + h * HD_ + d] =
                    __float2bfloat16(O[mh][dt][r] * inv);
            }
        }
}

// ---------------------------------------------------------------------------
// Kernel 5: out[m][n] = sum_k ctx[m][k] * W[n][k] + bias[n], fp32 out.
// 128x128 block tile, BK=32. 4 waves in 2x2; each wave computes a 64x64
// quadrant as 4x4 grid of 16x16 MFMA tiles (acc[4][4]).
// ---------------------------------------------------------------------------
__global__ __launch_bounds__(256) void proj(
    const __hip_bfloat16* __restrict__ ctx, const __hip_bfloat16* __restrict__ wb,
    const float* __restrict__ bias, float* __restrict__ out)
{
    __shared__ __hip_bfloat16 As[128][32];   // [m][k] 8KB
    __shared__ __hip_bfloat16 Bs[128][32];   // [n][k] 8KB

    const int m0 = blockIdx.x * 128;
    const int n0 = blockIdx.y * 128;
    const int tid  = threadIdx.x;
    const int wv   = tid >> 6;
    const int lane = tid & 63;
    const int l16  = lane & 15;
    const int quad = lane >> 4;
    const int wr   = (wv >> 1) * 64;     // wave row offset in tile
    const int wc   = (wv & 1) * 64;      // wave col offset in tile

    const int srow = tid >> 1;           // staging row 0..127
    const int scol = (tid & 1) * 16;     // 16 bf16 = 32B per thread

    floatx4 acc[4][4] = {};

    for (int k0 = 0; k0 < E_; k0 += 32) {
        const uint4* ap = (const uint4*)(ctx + (size_t)(m0 + srow) * E_ + k0 + scol);
        const uint4* bp = (const uint4*)(wb  + (size_t)(n0 + srow) * E_ + k0 + scol);
        uint4 a0 = ap[0], a1 = ap[1];
        uint4 b0 = bp[0], b1 = bp[1];
        *(uint4*)&As[srow][scol]     = a0;
        *(uint4*)&As[srow][scol + 8] = a1;
        *(uint4*)&Bs[srow][scol]     = b0;
        *(uint4*)&Bs[srow][scol + 8] = b1;
        __syncthreads();

        shortx8 af[4], bf[4];
#pragma unroll
        for (int mt = 0; mt < 4; ++mt)
            af[mt] = *(const shortx8*)&As[wr + mt * 16 + l16][quad * 8];
#pragma unroll
        for (int nt = 0; nt < 4; ++nt)
            bf[nt] = *(const shortx8*)&Bs[wc + nt * 16 + l16][quad * 8];

#pragma unroll
        for (int mt = 0; mt < 4; ++mt)
#pragma unroll
            for (int nt = 0; nt < 4; ++nt)
                acc[mt][nt] = __builtin_amdgcn_mfma_f32_16x16x32_bf16(
                    af[mt], bf[nt], acc[mt][nt], 0, 0, 0);
        __syncthreads();
    }

#pragma unroll
    for (int mt = 0; mt < 4; ++mt)
#pragma unroll
        for (int nt = 0; nt < 4; ++nt)
#pragma unroll
            for (int r = 0; r < 4; ++r) {
                const int mrow = m0 + wr + mt * 16 + quad * 4 + r;
                const int ncol = n0 + wc + nt * 16 + l16;
                out[(size_t)mrow * E_ + ncol] = acc[mt][nt][r] + bias[ncol];
            }
}

// ---------------------------------------------------------------------------
extern "C" void kernel_launch(void* const* d_in, const int* in_sizes, int n_in,
                              void* d_out, int out_size, void* d_ws, size_t ws_size,
                              hipStream_t stream)
{
    const float* q  = (const float*)d_in[0];
    const float* k  = (const float*)d_in[1];
    const float* v  = (const float*)d_in[2];
    const float* qw = (const float*)d_in[3];
    const float* kw = (const float*)d_in[4];
    const float* pw = (const float*)d_in[5];
    const float* pb = (const float*)d_in[6];
    float* out = (float*)d_out;

    char* ws = (char*)d_ws;
    const size_t SEG = (size_t)B_ * H_ * S_ * HD_ * 2;   // 16 MiB
    __hip_bfloat16* qh  = (__hip_bfloat16*)(ws);
    __hip_bfloat16* kh  = (__hip_bfloat16*)(ws + SEG);
    __hip_bfloat16* vt  = (__hip_bfloat16*)(ws + 2 * SEG);
    __hip_bfloat16* ctx = (__hip_bfloat16*)(ws + 3 * SEG);
    __hip_bfloat16* wbp = (__hip_bfloat16*)(ws + 4 * SEG);

    qk_prep<<<dim3(2 * B_ * S_ * E_ / 4 / 256), 256, 0, stream>>>(q, k, qw, kw, qh, kh);
    v_trans<<<dim3(S_ / 64, B_ * H_), 256, 0, stream>>>(v, vt);
    wconv<<<dim3(E_ * E_ / 4 / 256), 256, 0, stream>>>(pw, wbp);
    attn<<<dim3(S_ / 128, B_ * H_), 256, 0, stream>>>(qh, kh, vt, ctx);
    proj<<<dim3(B_ * S_ / 128, E_ / 128), 256, 0, stream>>>(ctx, wbp, pb, out);
}

// Round 5
// 321.246 us; speedup vs baseline: 1.0571x; 1.0571x over previous
//
#include <hip/hip_runtime.h>
#include <hip/hip_bf16.h>
#include <cstdint>

#define B_ 4
#define S_ 2048
#define E_ 1024
#define H_ 16
#define HD_ 64
#define EPS_ 1.1920928955078125e-07f

typedef __attribute__((ext_vector_type(8))) short shortx8;
typedef __attribute__((ext_vector_type(4))) float floatx4;
typedef __attribute__((ext_vector_type(4))) _Float16 halfx4;

// softmax scale folded into Q at prep time: Q *= 0.125*log2(e), so
// P = exp2(QK^T) directly. |logit*0.125| <= 8 (Cauchy-Schwarz after RMSNorm)
// so p <= e^8 ~ 2981 -- in fp16 range; normalization divides it out.
#define C1_ 0.18033688068389154f   // 0.125 * log2(e)

// ---------------------------------------------------------------------------
// Kernel 1: fused RMSNorm + RoPE for q and k, cast to bf16, transpose to
// [B,H,S,HD]. One thread per 4 consecutive elements; one 16-lane quad per
// head-vector (HD=64). Q pre-scaled by C1_.
// ---------------------------------------------------------------------------
__global__ __launch_bounds__(256) void qk_prep(
    const float* __restrict__ q, const float* __restrict__ k,
    const float* __restrict__ qw, const float* __restrict__ kw,
    __hip_bfloat16* __restrict__ qh, __hip_bfloat16* __restrict__ kh)
{
    const size_t PT = (size_t)B_ * S_ * E_ / 4;
    size_t t = (size_t)blockIdx.x * 256 + threadIdx.x;
    const bool is_k = (t >= PT);
    if (is_k) t -= PT;

    const int row = (int)(t >> 8);
    const int b   = row / S_;
    const int s   = row % S_;
    const int grp = (int)(t & 255);
    const int h   = grp >> 4;
    const int dl  = (grp & 15) * 4;

    const float* __restrict__ src = is_k ? k : q;
    const float* __restrict__ w   = is_k ? kw : qw;
    __hip_bfloat16* __restrict__ dst = is_k ? kh : qh;

    const float4 x  = ((const float4*)src)[t];
    const float4 wv = ((const float4*)w)[grp & 15];

    float ss = x.x * x.x + x.y * x.y + x.z * x.z + x.w * x.w;
#pragma unroll
    for (int m = 1; m < 16; m <<= 1) ss += __shfl_xor(ss, m);
    float r = rsqrtf(ss * (1.0f / HD_) + EPS_);
    if (!is_k) r *= C1_;

    const float xn0 = x.x * r * wv.x;
    const float xn1 = x.y * r * wv.y;
    const float xn2 = x.z * r * wv.z;
    const float xn3 = x.w * r * wv.w;

    const float L2I = 0.41524101186092029f;   // log2(10000)/32
    const int   i0  = dl >> 1;
    const float f0  = (float)s * exp2f(-(float)i0 * L2I);
    const float f1  = (float)s * exp2f(-(float)(i0 + 1) * L2I);
    const float c0 = cosf(f0), sn0 = sinf(f0);
    const float c1 = cosf(f1), sn1 = sinf(f1);

    __hip_bfloat16 pk[4];
    pk[0] = __float2bfloat16(xn0 * c0 - xn1 * sn0);
    pk[1] = __float2bfloat16(xn0 * sn0 + xn1 * c0);
    pk[2] = __float2bfloat16(xn2 * c1 - xn3 * sn1);
    pk[3] = __float2bfloat16(xn2 * sn1 + xn3 * c1);
    *(ushort4*)(dst + ((size_t)((b * H_ + h) * S_ + s)) * HD_ + dl) =
        *(const ushort4*)pk;
}

// ---------------------------------------------------------------------------
// Kernel 2: transpose V to [B,H,HD,S] as fp16 via LDS 64x64 tile.
// ---------------------------------------------------------------------------
__global__ __launch_bounds__(256) void v_trans(
    const float* __restrict__ v, _Float16* __restrict__ vt)
{
    __shared__ _Float16 tile[64][72];

    const int bh = blockIdx.y;
    const int s0 = blockIdx.x * 64;
    const int b  = bh >> 4, h = bh & 15;
    const int t  = threadIdx.x;

    {
        const int sl = t >> 2;
        const int d0 = (t & 3) * 16;
        const float* __restrict__ src =
            v + ((size_t)(b * S_ + s0 + sl)) * E_ + h * HD_ + d0;
        float4 f0 = ((const float4*)src)[0];
        float4 f1 = ((const float4*)src)[1];
        float4 f2 = ((const float4*)src)[2];
        float4 f3 = ((const float4*)src)[3];
        float vals[16] = {f0.x,f0.y,f0.z,f0.w, f1.x,f1.y,f1.z,f1.w,
                          f2.x,f2.y,f2.z,f2.w, f3.x,f3.y,f3.z,f3.w};
#pragma unroll
        for (int j = 0; j < 16; ++j)
            tile[d0 + j][sl] = (_Float16)vals[j];
    }
    __syncthreads();
    {
        const int d  = t >> 2;
        const int sg = (t & 3) * 16;
        _Float16* __restrict__ dst =
            vt + ((size_t)(bh * HD_ + d)) * S_ + s0 + sg;
        ((uint4*)dst)[0] = *(const uint4*)&tile[d][sg];
        ((uint4*)dst)[1] = *(const uint4*)&tile[d][sg + 8];
    }
}

// ---------------------------------------------------------------------------
// Kernel 3: proj_w fp32 -> bf16
// ---------------------------------------------------------------------------
__global__ __launch_bounds__(256) void wconv(
    const float* __restrict__ w, __hip_bfloat16* __restrict__ wb)
{
    const int i = blockIdx.x * 256 + threadIdx.x;
    float4 f = ((const float4*)w)[i];
    wb[4 * i + 0] = __float2bfloat16(f.x);
    wb[4 * i + 1] = __float2bfloat16(f.y);
    wb[4 * i + 2] = __float2bfloat16(f.z);
    wb[4 * i + 3] = __float2bfloat16(f.w);
}

// ---------------------------------------------------------------------------
// Kernel 4: flash attention via the S^T trick (no P LDS round-trip).
//   S^T = K*Q^T with mfma_f32_16x16x32_bf16(A=K_frag, B=Q_frag):
//     C gives S^T[key=quad*4+r][q=l16] -- which IS the B-operand layout of
//     the K=16 MFMA shape. So P^T = exp2(S^T) feeds
//     O^T = V^T * P^T via mfma_f32_16x16x16f16(A=V^T_frag, B=P^T) directly.
//   Row sums l: in-register adds + 2 quad shuffles. O^T lanes hold 4
//   consecutive d -> 8B vectorized ctx stores.
// Block = 4 waves * 32 q-rows = BM 128; K/V tiles of 64.
// ---------------------------------------------------------------------------
__global__ __launch_bounds__(256) void attn(
    const __hip_bfloat16* __restrict__ qh, const __hip_bfloat16* __restrict__ kh,
    const _Float16* __restrict__ vt, __hip_bfloat16* __restrict__ ctx)
{
    __shared__ __hip_bfloat16 Kt[64][72];   // [key][d]   9.2 KB
    __shared__ _Float16       Vt[64][88];   // [d][key]  11.3 KB

    const int bh   = blockIdx.y;
    const int q0   = blockIdx.x * 128;
    const int tid  = threadIdx.x;
    const int wv   = tid >> 6;
    const int lane = tid & 63;
    const int l16  = lane & 15;
    const int quad = lane >> 4;
    const int b    = bh >> 4, h = bh & 15;

    // Q fragments: two 16-row halves of this wave's 32 rows
    shortx8 aq[2][2];
#pragma unroll
    for (int mh = 0; mh < 2; ++mh) {
        const __hip_bfloat16* qbase =
            qh + ((size_t)bh * S_ + q0 + wv * 32 + mh * 16 + l16) * HD_;
        aq[mh][0] = *(const shortx8*)(qbase + quad * 8);
        aq[mh][1] = *(const shortx8*)(qbase + 32 + quad * 8);
    }

    floatx4 O[2][4] = {};     // O^T accumulators [m-half][d-tile]
    float l_acc[2] = {0.f, 0.f};

    const __hip_bfloat16* __restrict__ kbase = kh + (size_t)bh * S_ * HD_;
    const _Float16* __restrict__ vbase = vt + (size_t)bh * HD_ * S_;

    const int sr = tid >> 2;
    const int sc = (tid & 3) * 16;

    for (int kt = 0; kt < S_ / 64; ++kt) {
        // ---- stage K [key][d] bf16 and V^T [d][key] fp16 ----
        const __hip_bfloat16* kp = kbase + ((size_t)(kt * 64 + sr)) * HD_ + sc;
        uint4 kv0 = *(const uint4*)kp;
        uint4 kv1 = *(const uint4*)(kp + 8);
        const _Float16* vp = vbase + (size_t)sr * S_ + kt * 64 + sc;
        uint4 vv0 = *(const uint4*)vp;
        uint4 vv1 = *(const uint4*)(vp + 8);
        *(uint4*)&Kt[sr][sc]     = kv0;
        *(uint4*)&Kt[sr][sc + 8] = kv1;
        *(uint4*)&Vt[sr][sc]     = vv0;
        *(uint4*)&Vt[sr][sc + 8] = vv1;
        __syncthreads();

        // ---- S^T = K * Q^T : per nt (16 keys), both m-halves ----
        floatx4 s4[2][4];
#pragma unroll
        for (int nt = 0; nt < 4; ++nt) {
            const shortx8 kb0 = *(const shortx8*)&Kt[nt * 16 + l16][quad * 8];
            const shortx8 kb1 = *(const shortx8*)&Kt[nt * 16 + l16][32 + quad * 8];
#pragma unroll
            for (int mh = 0; mh < 2; ++mh) {
                floatx4 c = {0.f, 0.f, 0.f, 0.f};
                c = __builtin_amdgcn_mfma_f32_16x16x32_bf16(kb0, aq[mh][0], c, 0, 0, 0);
                c = __builtin_amdgcn_mfma_f32_16x16x32_bf16(kb1, aq[mh][1], c, 0, 0, 0);
                s4[mh][nt] = c;
            }
        }

        // ---- P^T = exp2(S^T): elementwise; already in B-layout (K=16) ----
        halfx4 pb[2][4];
#pragma unroll
        for (int mh = 0; mh < 2; ++mh) {
            float ls = 0.f;
#pragma unroll
            for (int kc = 0; kc < 4; ++kc) {
                halfx4 hp;
#pragma unroll
                for (int r = 0; r < 4; ++r) {
                    const float p = exp2f(s4[mh][kc][r]);
                    ls += p;
                    hp[r] = (_Float16)p;
                }
                pb[mh][kc] = hp;
            }
            // column sum for q=l16: combine the 4 quads
            ls += __shfl_xor(ls, 16);
            ls += __shfl_xor(ls, 32);
            l_acc[mh] += ls;
        }

        // ---- O^T += V^T * P^T (16x16x16 f16) ----
#pragma unroll
        for (int dt = 0; dt < 4; ++dt) {
#pragma unroll
            for (int kc = 0; kc < 4; ++kc) {
                const halfx4 vb =
                    *(const halfx4*)&Vt[dt * 16 + l16][kc * 16 + quad * 4];
#pragma unroll
                for (int mh = 0; mh < 2; ++mh)
                    O[mh][dt] = __builtin_amdgcn_mfma_f32_16x16x16f16(
                        vb, pb[mh][kc], O[mh][dt], 0, 0, 0);
            }
        }
        __syncthreads();
    }

    // ---- epilogue: normalize, vectorized 8B stores ----
#pragma unroll
    for (int mh = 0; mh < 2; ++mh) {
        const float inv = 1.0f / l_acc[mh];
        const int s = q0 + wv * 32 + mh * 16 + l16;       // q = l16
        __hip_bfloat16* cb = ctx + ((size_t)(b * S_ + s)) * E_ + h * HD_;
#pragma unroll
        for (int dt = 0; dt < 4; ++dt) {
            __hip_bfloat16 pk[4];
#pragma unroll
            for (int r = 0; r < 4; ++r)
                pk[r] = __float2bfloat16(O[mh][dt][r] * inv);
            *(ushort4*)(cb + dt * 16 + quad * 4) = *(const ushort4*)pk;
        }
    }
}

// ---------------------------------------------------------------------------
// Kernel 5: out[m][n] = sum_k ctx[m][k] * W[n][k] + bias[n], fp32 out.
// 64x128 tile (grid 1024 = 4 blocks/CU), BK=32, padded LDS stride 40.
// 4 waves side-by-side in n; each wave 64x32 (acc[4][2]).
// ---------------------------------------------------------------------------
__global__ __launch_bounds__(256) void proj(
    const __hip_bfloat16* __restrict__ ctx, const __hip_bfloat16* __restrict__ wb,
    const float* __restrict__ bias, float* __restrict__ out)
{
    __shared__ __hip_bfloat16 As[64][40];    // [m][k]
    __shared__ __hip_bfloat16 Bs[128][40];   // [n][k]

    const int m0 = blockIdx.x * 64;
    const int n0 = blockIdx.y * 128;
    const int tid  = threadIdx.x;
    const int wv   = tid >> 6;
    const int lane = tid & 63;
    const int l16  = lane & 15;
    const int quad = lane >> 4;
    const int wc   = wv * 32;            // wave col offset

    const int ar = tid >> 2, ac = (tid & 3) * 8;    // As staging
    const int br = tid >> 1, bc = (tid & 1) * 16;   // Bs staging

    floatx4 acc[4][2] = {};

    for (int k0 = 0; k0 < E_; k0 += 32) {
        const uint4 av = *(const uint4*)(ctx + (size_t)(m0 + ar) * E_ + k0 + ac);
        const uint4* bp = (const uint4*)(wb + (size_t)(n0 + br) * E_ + k0 + bc);
        uint4 b0 = bp[0], b1 = bp[1];
        *(uint4*)&As[ar][ac]     = av;
        *(uint4*)&Bs[br][bc]     = b0;
        *(uint4*)&Bs[br][bc + 8] = b1;
        __syncthreads();

        shortx8 af[4], bf[2];
#pragma unroll
        for (int mt = 0; mt < 4; ++mt)
            af[mt] = *(const shortx8*)&As[mt * 16 + l16][quad * 8];
#pragma unroll
        for (int nt = 0; nt < 2; ++nt)
            bf[nt] = *(const shortx8*)&Bs[wc + nt * 16 + l16][quad * 8];

#pragma unroll
        for (int mt = 0; mt < 4; ++mt)
#pragma unroll
            for (int nt = 0; nt < 2; ++nt)
                acc[mt][nt] = __builtin_amdgcn_mfma_f32_16x16x32_bf16(
                    af[mt], bf[nt], acc[mt][nt], 0, 0, 0);
        __syncthreads();
    }

#pragma unroll
    for (int mt = 0; mt < 4; ++mt)
#pragma unroll
        for (int nt = 0; nt < 2; ++nt)
#pragma unroll
            for (int r = 0; r < 4; ++r) {
                const int mrow = m0 + mt * 16 + quad * 4 + r;
                const int ncol = n0 + wc + nt * 16 + l16;
                out[(size_t)mrow * E_ + ncol] = acc[mt][nt][r] + bias[ncol];
            }
}

// ---------------------------------------------------------------------------
extern "C" void kernel_launch(void* const* d_in, const int* in_sizes, int n_in,
                              void* d_out, int out_size, void* d_ws, size_t ws_size,
                              hipStream_t stream)
{
    const float* q  = (const float*)d_in[0];
    const float* k  = (const float*)d_in[1];
    const float* v  = (const float*)d_in[2];
    const float* qw = (const float*)d_in[3];
    const float* kw = (const float*)d_in[4];
    const float* pw = (const float*)d_in[5];
    const float* pb = (const float*)d_in[6];
    float* out = (float*)d_out;

    char* ws = (char*)d_ws;
    const size_t SEG = (size_t)B_ * H_ * S_ * HD_ * 2;   // 16 MiB
    __hip_bfloat16* qh  = (__hip_bfloat16*)(ws);
    __hip_bfloat16* kh  = (__hip_bfloat16*)(ws + SEG);
    _Float16*       vt  = (_Float16*)(ws + 2 * SEG);
    __hip_bfloat16* ctx = (__hip_bfloat16*)(ws + 3 * SEG);
    __hip_bfloat16* wbp = (__hip_bfloat16*)(ws + 4 * SEG);

    qk_prep<<<dim3(2 * B_ * S_ * E_ / 4 / 256), 256, 0, stream>>>(q, k, qw, kw, qh, kh);
    v_trans<<<dim3(S_ / 64, B_ * H_), 256, 0, stream>>>(v, vt);
    wconv<<<dim3(E_ * E_ / 4 / 256), 256, 0, stream>>>(pw, wbp);
    attn<<<dim3(S_ / 128, B_ * H_), 256, 0, stream>>>(qh, kh, vt, ctx);
    proj<<<dim3(B_ * S_ / 64, E_ / 128), 256, 0, stream>>>(ctx, wbp, pb, out);
}

// Round 6
// 317.665 us; speedup vs baseline: 1.0690x; 1.0113x over previous
//
#include <hip/hip_runtime.h>
#include <hip/hip_bf16.h>
#include <cstdint>

#define B_ 4
#define S_ 2048
#define E_ 1024
#define H_ 16
#define HD_ 64
#define EPS_ 1.1920928955078125e-07f

typedef __attribute__((ext_vector_type(8))) short shortx8;
typedef __attribute__((ext_vector_type(4))) float floatx4;
typedef __attribute__((ext_vector_type(4))) _Float16 halfx4;
typedef __attribute__((ext_vector_type(8))) _Float16 halfx8;

// softmax scale folded into Q at prep time: Q *= 0.125*log2(e), so
// P = exp2(QK^T) directly. |logit*0.125| <= 8 (Cauchy-Schwarz after RMSNorm)
// so p <= e^8 ~ 2981 -- in fp16 range; normalization divides it out.
#define C1_ 0.18033688068389154f   // 0.125 * log2(e)

// ---------------------------------------------------------------------------
// Kernel 1: fused RMSNorm + RoPE for q and k, cast to bf16, transpose to
// [B,H,S,HD]. One thread per 4 consecutive elements; one 16-lane quad per
// head-vector (HD=64). Q pre-scaled by C1_. Native __sinf/__cosf (accuracy
// ~2^-15 abs, well under bf16's 2^-8).
// ---------------------------------------------------------------------------
__global__ __launch_bounds__(256) void qk_prep(
    const float* __restrict__ q, const float* __restrict__ k,
    const float* __restrict__ qw, const float* __restrict__ kw,
    __hip_bfloat16* __restrict__ qh, __hip_bfloat16* __restrict__ kh)
{
    const size_t PT = (size_t)B_ * S_ * E_ / 4;
    size_t t = (size_t)blockIdx.x * 256 + threadIdx.x;
    const bool is_k = (t >= PT);
    if (is_k) t -= PT;

    const int row = (int)(t >> 8);
    const int b   = row / S_;
    const int s   = row % S_;
    const int grp = (int)(t & 255);
    const int h   = grp >> 4;
    const int dl  = (grp & 15) * 4;

    const float* __restrict__ src = is_k ? k : q;
    const float* __restrict__ w   = is_k ? kw : qw;
    __hip_bfloat16* __restrict__ dst = is_k ? kh : qh;

    const float4 x  = ((const float4*)src)[t];
    const float4 wv = ((const float4*)w)[grp & 15];

    float ss = x.x * x.x + x.y * x.y + x.z * x.z + x.w * x.w;
#pragma unroll
    for (int m = 1; m < 16; m <<= 1) ss += __shfl_xor(ss, m);
    float r = rsqrtf(ss * (1.0f / HD_) + EPS_);
    if (!is_k) r *= C1_;

    const float xn0 = x.x * r * wv.x;
    const float xn1 = x.y * r * wv.y;
    const float xn2 = x.z * r * wv.z;
    const float xn3 = x.w * r * wv.w;

    const float L2I = 0.41524101186092029f;   // log2(10000)/32
    const int   i0  = dl >> 1;
    const float f0  = (float)s * exp2f(-(float)i0 * L2I);
    const float f1  = (float)s * exp2f(-(float)(i0 + 1) * L2I);
    const float c0 = __cosf(f0), sn0 = __sinf(f0);
    const float c1 = __cosf(f1), sn1 = __sinf(f1);

    __hip_bfloat16 pk[4];
    pk[0] = __float2bfloat16(xn0 * c0 - xn1 * sn0);
    pk[1] = __float2bfloat16(xn0 * sn0 + xn1 * c0);
    pk[2] = __float2bfloat16(xn2 * c1 - xn3 * sn1);
    pk[3] = __float2bfloat16(xn2 * sn1 + xn3 * c1);
    *(ushort4*)(dst + ((size_t)((b * H_ + h) * S_ + s)) * HD_ + dl) =
        *(const ushort4*)pk;
}

// ---------------------------------------------------------------------------
// Kernel 2: transpose V to [B,H,HD,S] as fp16 via LDS 64x64 tile.
// ---------------------------------------------------------------------------
__global__ __launch_bounds__(256) void v_trans(
    const float* __restrict__ v, _Float16* __restrict__ vt)
{
    __shared__ _Float16 tile[64][72];

    const int bh = blockIdx.y;
    const int s0 = blockIdx.x * 64;
    const int b  = bh >> 4, h = bh & 15;
    const int t  = threadIdx.x;

    {
        const int sl = t >> 2;
        const int d0 = (t & 3) * 16;
        const float* __restrict__ src =
            v + ((size_t)(b * S_ + s0 + sl)) * E_ + h * HD_ + d0;
        float4 f0 = ((const float4*)src)[0];
        float4 f1 = ((const float4*)src)[1];
        float4 f2 = ((const float4*)src)[2];
        float4 f3 = ((const float4*)src)[3];
        float vals[16] = {f0.x,f0.y,f0.z,f0.w, f1.x,f1.y,f1.z,f1.w,
                          f2.x,f2.y,f2.z,f2.w, f3.x,f3.y,f3.z,f3.w};
#pragma unroll
        for (int j = 0; j < 16; ++j)
            tile[d0 + j][sl] = (_Float16)vals[j];
    }
    __syncthreads();
    {
        const int d  = t >> 2;
        const int sg = (t & 3) * 16;
        _Float16* __restrict__ dst =
            vt + ((size_t)(bh * HD_ + d)) * S_ + s0 + sg;
        ((uint4*)dst)[0] = *(const uint4*)&tile[d][sg];
        ((uint4*)dst)[1] = *(const uint4*)&tile[d][sg + 8];
    }
}

// ---------------------------------------------------------------------------
// Kernel 3: proj_w fp32 -> bf16
// ---------------------------------------------------------------------------
__global__ __launch_bounds__(256) void wconv(
    const float* __restrict__ w, __hip_bfloat16* __restrict__ wb)
{
    const int i = blockIdx.x * 256 + threadIdx.x;
    float4 f = ((const float4*)w)[i];
    wb[4 * i + 0] = __float2bfloat16(f.x);
    wb[4 * i + 1] = __float2bfloat16(f.y);
    wb[4 * i + 2] = __float2bfloat16(f.z);
    wb[4 * i + 3] = __float2bfloat16(f.w);
}

// ---------------------------------------------------------------------------
// Kernel 4: flash attention, S^T trick + K=32 PV via key permutation.
//   S^T = K*Q^T (mfma 16x16x32 bf16, A=K B=Q): C[key=quad*4+r][q=l16].
//   PV at K=32 f16: MFMA only needs A,B to AGREE on which key occupies
//   slot (quad,j). B-frag: j<4 <- s4[2f] reg j (key quad*4+j),
//   j>=4 <- s4[2f+1] reg j-4 (key 16+quad*4+j-4). A-frag (V^T) loads the
//   matching permuted columns: offsets quad*4 + {0,16} (+{32,48} for f=1).
//   128-key staging tiles halve barrier count. mh (two 16-q halves)
//   processed sequentially to cap VGPR.
// ---------------------------------------------------------------------------
__global__ __launch_bounds__(256) void attn(
    const __hip_bfloat16* __restrict__ qh, const __hip_bfloat16* __restrict__ kh,
    const _Float16* __restrict__ vt, __hip_bfloat16* __restrict__ ctx)
{
    __shared__ __hip_bfloat16 Kt[128][72];   // [key][d]   18.4 KB, 144B rows
    __shared__ _Float16       Vt[64][152];   // [d][key]   19.0 KB, 304B rows

    const int bh   = blockIdx.y;
    const int q0   = blockIdx.x * 128;
    const int tid  = threadIdx.x;
    const int wv   = tid >> 6;
    const int lane = tid & 63;
    const int l16  = lane & 15;
    const int quad = lane >> 4;
    const int b    = bh >> 4, h = bh & 15;

    // Q fragments: two 16-row halves of this wave's 32 rows
    shortx8 aq[2][2];
#pragma unroll
    for (int mh = 0; mh < 2; ++mh) {
        const __hip_bfloat16* qbase =
            qh + ((size_t)bh * S_ + q0 + wv * 32 + mh * 16 + l16) * HD_;
        aq[mh][0] = *(const shortx8*)(qbase + quad * 8);
        aq[mh][1] = *(const shortx8*)(qbase + 32 + quad * 8);
    }

    floatx4 O[2][4] = {};     // O^T accumulators [m-half][d-tile]
    float l_acc[2] = {0.f, 0.f};

    const __hip_bfloat16* __restrict__ kbase = kh + (size_t)bh * S_ * HD_;
    const _Float16* __restrict__ vbase = vt + (size_t)bh * HD_ * S_;

    const int sr = tid >> 1, sc = (tid & 1) * 32;   // K staging: 128 rows x 64
    const int vr = tid >> 2, vc = (tid & 3) * 32;   // V staging: 64 rows x 128

    for (int kt = 0; kt < S_ / 128; ++kt) {
        // ---- stage K [128 keys][64 d] bf16 and V^T [64 d][128 keys] fp16 ----
        {
            const __hip_bfloat16* kp = kbase + ((size_t)(kt * 128 + sr)) * HD_ + sc;
            uint4 k0 = ((const uint4*)kp)[0];
            uint4 k1 = ((const uint4*)kp)[1];
            uint4 k2 = ((const uint4*)kp)[2];
            uint4 k3 = ((const uint4*)kp)[3];
            *(uint4*)&Kt[sr][sc]      = k0;
            *(uint4*)&Kt[sr][sc + 8]  = k1;
            *(uint4*)&Kt[sr][sc + 16] = k2;
            *(uint4*)&Kt[sr][sc + 24] = k3;
            const _Float16* vp = vbase + (size_t)vr * S_ + kt * 128 + vc;
            uint4 v0 = ((const uint4*)vp)[0];
            uint4 v1 = ((const uint4*)vp)[1];
            uint4 v2 = ((const uint4*)vp)[2];
            uint4 v3 = ((const uint4*)vp)[3];
            *(uint4*)&Vt[vr][vc]      = v0;
            *(uint4*)&Vt[vr][vc + 8]  = v1;
            *(uint4*)&Vt[vr][vc + 16] = v2;
            *(uint4*)&Vt[vr][vc + 24] = v3;
        }
        __syncthreads();

#pragma unroll
        for (int hk = 0; hk < 2; ++hk) {          // two 64-key halves
#pragma unroll
            for (int mh = 0; mh < 2; ++mh) {      // two 16-q halves
                // ---- S^T = K * Q^T over 64 keys ----
                floatx4 s4[4];
#pragma unroll
                for (int nt = 0; nt < 4; ++nt) {
                    const shortx8 kb0 =
                        *(const shortx8*)&Kt[hk * 64 + nt * 16 + l16][quad * 8];
                    const shortx8 kb1 =
                        *(const shortx8*)&Kt[hk * 64 + nt * 16 + l16][32 + quad * 8];
                    floatx4 c = {0.f, 0.f, 0.f, 0.f};
                    c = __builtin_amdgcn_mfma_f32_16x16x32_bf16(kb0, aq[mh][0], c, 0, 0, 0);
                    c = __builtin_amdgcn_mfma_f32_16x16x32_bf16(kb1, aq[mh][1], c, 0, 0, 0);
                    s4[nt] = c;
                }

                // ---- P^T = exp2(S^T), packed as two K=32 B-frags ----
                halfx8 bb[2];
                float ls = 0.f;
#pragma unroll
                for (int f = 0; f < 2; ++f) {
                    halfx8 hb;
#pragma unroll
                    for (int r = 0; r < 4; ++r) {
                        const float p = exp2f(s4[2 * f][r]);
                        ls += p; hb[r] = (_Float16)p;
                    }
#pragma unroll
                    for (int r = 0; r < 4; ++r) {
                        const float p = exp2f(s4[2 * f + 1][r]);
                        ls += p; hb[4 + r] = (_Float16)p;
                    }
                    bb[f] = hb;
                }
                ls += __shfl_xor(ls, 16);
                ls += __shfl_xor(ls, 32);
                l_acc[mh] += ls;

                // ---- O^T += V^T * P^T  (16x16x32 f16, permuted keys) ----
#pragma unroll
                for (int dt = 0; dt < 4; ++dt) {
                    const _Float16* vrow = &Vt[dt * 16 + l16][hk * 64];
                    const halfx4 a0 = *(const halfx4*)(vrow + quad * 4);
                    const halfx4 a1 = *(const halfx4*)(vrow + 16 + quad * 4);
                    const halfx4 a2 = *(const halfx4*)(vrow + 32 + quad * 4);
                    const halfx4 a3 = *(const halfx4*)(vrow + 48 + quad * 4);
                    const halfx8 A0 = __builtin_shufflevector(a0, a1, 0,1,2,3,4,5,6,7);
                    const halfx8 A1 = __builtin_shufflevector(a2, a3, 0,1,2,3,4,5,6,7);
                    O[mh][dt] = __builtin_amdgcn_mfma_f32_16x16x32_f16(
                        A0, bb[0], O[mh][dt], 0, 0, 0);
                    O[mh][dt] = __builtin_amdgcn_mfma_f32_16x16x32_f16(
                        A1, bb[1], O[mh][dt], 0, 0, 0);
                }
            }
        }
        __syncthreads();
    }

    // ---- epilogue: normalize, vectorized 8B stores (O^T: lane = d-major) ----
#pragma unroll
    for (int mh = 0; mh < 2; ++mh) {
        const float inv = 1.0f / l_acc[mh];
        const int s = q0 + wv * 32 + mh * 16 + l16;       // q = l16
        __hip_bfloat16* cb = ctx + ((size_t)(b * S_ + s)) * E_ + h * HD_;
#pragma unroll
        for (int dt = 0; dt < 4; ++dt) {
            __hip_bfloat16 pk[4];
#pragma unroll
            for (int r = 0; r < 4; ++r)
                pk[r] = __float2bfloat16(O[mh][dt][r] * inv);
            *(ushort4*)(cb + dt * 16 + quad * 4) = *(const ushort4*)pk;
        }
    }
}

// ---------------------------------------------------------------------------
// Kernel 5: out[m][n] = sum_k ctx[m][k] * W[n][k] + bias[n], fp32 out.
// 128x128 tile, BK=32, LDS stride 40 (20 banks -> 2-way, free). 4 waves 2x2;
// each wave 64x64 quadrant = acc[4][4]; 16 MFMA between barriers.
// ---------------------------------------------------------------------------
__global__ __launch_bounds__(256) void proj(
    const __hip_bfloat16* __restrict__ ctx, const __hip_bfloat16* __restrict__ wb,
    const float* __restrict__ bias, float* __restrict__ out)
{
    __shared__ __hip_bfloat16 As[128][40];   // [m][k] 10 KB
    __shared__ __hip_bfloat16 Bs[128][40];   // [n][k] 10 KB

    const int m0 = blockIdx.x * 128;
    const int n0 = blockIdx.y * 128;
    const int tid  = threadIdx.x;
    const int wv   = tid >> 6;
    const int lane = tid & 63;
    const int l16  = lane & 15;
    const int quad = lane >> 4;
    const int wr   = (wv >> 1) * 64;
    const int wc   = (wv & 1) * 64;

    const int srow = tid >> 1;
    const int scol = (tid & 1) * 16;

    floatx4 acc[4][4] = {};

    for (int k0 = 0; k0 < E_; k0 += 32) {
        const uint4* ap = (const uint4*)(ctx + (size_t)(m0 + srow) * E_ + k0 + scol);
        const uint4* bp = (const uint4*)(wb  + (size_t)(n0 + srow) * E_ + k0 + scol);
        uint4 a0 = ap[0], a1 = ap[1];
        uint4 b0 = bp[0], b1 = bp[1];
        *(uint4*)&As[srow][scol]     = a0;
        *(uint4*)&As[srow][scol + 8] = a1;
        *(uint4*)&Bs[srow][scol]     = b0;
        *(uint4*)&Bs[srow][scol + 8] = b1;
        __syncthreads();

        shortx8 af[4], bf[4];
#pragma unroll
        for (int mt = 0; mt < 4; ++mt)
            af[mt] = *(const shortx8*)&As[wr + mt * 16 + l16][quad * 8];
#pragma unroll
        for (int nt = 0; nt < 4; ++nt)
            bf[nt] = *(const shortx8*)&Bs[wc + nt * 16 + l16][quad * 8];

#pragma unroll
        for (int mt = 0; mt < 4; ++mt)
#pragma unroll
            for (int nt = 0; nt < 4; ++nt)
                acc[mt][nt] = __builtin_amdgcn_mfma_f32_16x16x32_bf16(
                    af[mt], bf[nt], acc[mt][nt], 0, 0, 0);
        __syncthreads();
    }

#pragma unroll
    for (int nt = 0; nt < 4; ++nt) {
        const float bv = bias[n0 + wc + nt * 16 + l16];
#pragma unroll
        for (int mt = 0; mt < 4; ++mt)
#pragma unroll
            for (int r = 0; r < 4; ++r) {
                const int mrow = m0 + wr + mt * 16 + quad * 4 + r;
                const int ncol = n0 + wc + nt * 16 + l16;
                out[(size_t)mrow * E_ + ncol] = acc[mt][nt][r] + bv;
            }
    }
}

// ---------------------------------------------------------------------------
extern "C" void kernel_launch(void* const* d_in, const int* in_sizes, int n_in,
                              void* d_out, int out_size, void* d_ws, size_t ws_size,
                              hipStream_t stream)
{
    const float* q  = (const float*)d_in[0];
    const float* k  = (const float*)d_in[1];
    const float* v  = (const float*)d_in[2];
    const float* qw = (const float*)d_in[3];
    const float* kw = (const float*)d_in[4];
    const float* pw = (const float*)d_in[5];
    const float* pb = (const float*)d_in[6];
    float* out = (float*)d_out;

    char* ws = (char*)d_ws;
    const size_t SEG = (size_t)B_ * H_ * S_ * HD_ * 2;   // 16 MiB
    __hip_bfloat16* qh  = (__hip_bfloat16*)(ws);
    __hip_bfloat16* kh  = (__hip_bfloat16*)(ws + SEG);
    _Float16*       vt  = (_Float16*)(ws + 2 * SEG);
    __hip_bfloat16* ctx = (__hip_bfloat16*)(ws + 3 * SEG);
    __hip_bfloat16* wbp = (__hip_bfloat16*)(ws + 4 * SEG);

    qk_prep<<<dim3(2 * B_ * S_ * E_ / 4 / 256), 256, 0, stream>>>(q, k, qw, kw, qh, kh);
    v_trans<<<dim3(S_ / 64, B_ * H_), 256, 0, stream>>>(v, vt);
    wconv<<<dim3(E_ * E_ / 4 / 256), 256, 0, stream>>>(pw, wbp);
    attn<<<dim3(S_ / 128, B_ * H_), 256, 0, stream>>>(qh, kh, vt, ctx);
    proj<<<dim3(B_ * S_ / 128, E_ / 128), 256, 0, stream>>>(ctx, wbp, pb, out);
}

// Round 8
// 279.897 us; speedup vs baseline: 1.2133x; 1.1349x over previous
//
#include <hip/hip_runtime.h>
#include <hip/hip_bf16.h>
#include <cstdint>

#define B_ 4
#define S_ 2048
#define E_ 1024
#define H_ 16
#define HD_ 64
#define EPS_ 1.1920928955078125e-07f

typedef __attribute__((ext_vector_type(8))) short shortx8;
typedef __attribute__((ext_vector_type(4))) float floatx4;
typedef __attribute__((ext_vector_type(4))) _Float16 halfx4;
typedef __attribute__((ext_vector_type(8))) _Float16 halfx8;

// softmax scale folded into Q at prep time: Q *= 0.125*log2(e), so
// P = exp2(QK^T) directly. |logit*0.125| <= 8 (Cauchy-Schwarz after RMSNorm)
// so p <= e^8 ~ 2981 -- in fp16 range; normalization divides it out.
#define C1_ 0.18033688068389154f   // 0.125 * log2(e)

// ---------------------------------------------------------------------------
// Kernel 1 (fused prep): three block-uniform jobs in one dispatch.
//   bid <  16384 : RMSNorm+RoPE q,k -> bf16 [B,H,S,HD] (Q pre-scaled C1_)
//   bid <  18432 : V transpose -> fp16 [B,H,HD,S]
//   else         : proj_w fp32 -> bf16
// ---------------------------------------------------------------------------
__global__ __launch_bounds__(256) void prep(
    const float* __restrict__ q, const float* __restrict__ k,
    const float* __restrict__ v,
    const float* __restrict__ qw, const float* __restrict__ kw,
    const float* __restrict__ pw,
    __hip_bfloat16* __restrict__ qh, __hip_bfloat16* __restrict__ kh,
    _Float16* __restrict__ vt, __hip_bfloat16* __restrict__ wb)
{
    __shared__ _Float16 tile[64][72];
    const int bid = blockIdx.x;
    const int tid = threadIdx.x;

    if (bid < 16384) {
        // ---- RMSNorm + RoPE ----
        const size_t PT = (size_t)B_ * S_ * E_ / 4;
        size_t t = (size_t)bid * 256 + tid;
        const bool is_k = (t >= PT);
        if (is_k) t -= PT;

        const int row = (int)(t >> 8);
        const int b   = row / S_;
        const int s   = row % S_;
        const int grp = (int)(t & 255);
        const int h   = grp >> 4;
        const int dl  = (grp & 15) * 4;

        const float* __restrict__ src = is_k ? k : q;
        const float* __restrict__ w   = is_k ? kw : qw;
        __hip_bfloat16* __restrict__ dst = is_k ? kh : qh;

        const float4 x  = ((const float4*)src)[t];
        const float4 wv = ((const float4*)w)[grp & 15];

        float ss = x.x * x.x + x.y * x.y + x.z * x.z + x.w * x.w;
#pragma unroll
        for (int m = 1; m < 16; m <<= 1) ss += __shfl_xor(ss, m);
        float r = rsqrtf(ss * (1.0f / HD_) + EPS_);
        if (!is_k) r *= C1_;

        const float xn0 = x.x * r * wv.x;
        const float xn1 = x.y * r * wv.y;
        const float xn2 = x.z * r * wv.z;
        const float xn3 = x.w * r * wv.w;

        const float L2I = 0.41524101186092029f;   // log2(10000)/32
        const int   i0  = dl >> 1;
        const float f0  = (float)s * exp2f(-(float)i0 * L2I);
        const float f1  = (float)s * exp2f(-(float)(i0 + 1) * L2I);
        const float c0 = __cosf(f0), sn0 = __sinf(f0);
        const float c1 = __cosf(f1), sn1 = __sinf(f1);

        __hip_bfloat16 pk[4];
        pk[0] = __float2bfloat16(xn0 * c0 - xn1 * sn0);
        pk[1] = __float2bfloat16(xn0 * sn0 + xn1 * c0);
        pk[2] = __float2bfloat16(xn2 * c1 - xn3 * sn1);
        pk[3] = __float2bfloat16(xn2 * sn1 + xn3 * c1);
        *(ushort4*)(dst + ((size_t)((b * H_ + h) * S_ + s)) * HD_ + dl) =
            *(const ushort4*)pk;
    } else if (bid < 18432) {
        // ---- V transpose ----
        const int bb2 = bid - 16384;
        const int s0  = (bb2 & 31) * 64;
        const int bh  = bb2 >> 5;
        const int b   = bh >> 4, h = bh & 15;
        {
            const int sl = tid >> 2;
            const int d0 = (tid & 3) * 16;
            const float* __restrict__ src =
                v + ((size_t)(b * S_ + s0 + sl)) * E_ + h * HD_ + d0;
            float4 f0 = ((const float4*)src)[0];
            float4 f1 = ((const float4*)src)[1];
            float4 f2 = ((const float4*)src)[2];
            float4 f3 = ((const float4*)src)[3];
            float vals[16] = {f0.x,f0.y,f0.z,f0.w, f1.x,f1.y,f1.z,f1.w,
                              f2.x,f2.y,f2.z,f2.w, f3.x,f3.y,f3.z,f3.w};
#pragma unroll
            for (int j = 0; j < 16; ++j)
                tile[d0 + j][sl] = (_Float16)vals[j];
        }
        __syncthreads();
        {
            const int d  = tid >> 2;
            const int sg = (tid & 3) * 16;
            _Float16* __restrict__ dst =
                vt + ((size_t)(bh * HD_ + d)) * S_ + s0 + sg;
            ((uint4*)dst)[0] = *(const uint4*)&tile[d][sg];
            ((uint4*)dst)[1] = *(const uint4*)&tile[d][sg + 8];
        }
    } else {
        // ---- W conv ----
        const int i = (bid - 18432) * 256 + tid;
        float4 f = ((const float4*)pw)[i];
        wb[4 * i + 0] = __float2bfloat16(f.x);
        wb[4 * i + 1] = __float2bfloat16(f.y);
        wb[4 * i + 2] = __float2bfloat16(f.z);
        wb[4 * i + 3] = __float2bfloat16(f.w);
    }
}

// ---------------------------------------------------------------------------
// Kernel 2: flash attention. S^T trick + K=32 f16 PV (key permutation),
// frags shared across both 16-q halves, row-sum l via constant-ones MFMA,
// XCD-swizzled 1D grid (each XCD owns 8 bh -> K/V working set = its 4MB L2).
//   S^T = K*Q^T (mfma 16x16x32 bf16, A=K B=Q): C[key=quad*4+r][q=l16].
//   PV: B-frag slot (quad,j): j<4 <- s4[2f] (key quad*4+j), j>=4 <- s4[2f+1]
//   (key 16+quad*4+j-4); V^T A-frag reads matching permuted columns.
//   l: A=ones(16x32) f16 -> C = column sums of P^T; per-lane, no shuffles.
// ---------------------------------------------------------------------------
__global__ __launch_bounds__(256, 4) void attn(
    const __hip_bfloat16* __restrict__ qh, const __hip_bfloat16* __restrict__ kh,
    const _Float16* __restrict__ vt, __hip_bfloat16* __restrict__ ctx)
{
    __shared__ __hip_bfloat16 Kt[128][72];   // [key][d]   18.4 KB
    __shared__ _Float16       Vt[64][152];   // [d][key]   19.0 KB

    const int bid  = blockIdx.x;
    const int slot = bid >> 3;
    const int bh   = ((bid & 7) << 3) | (slot & 7);   // XCD-local bh
    const int q0   = (slot >> 3) * 128;
    const int tid  = threadIdx.x;
    const int wv   = tid >> 6;
    const int lane = tid & 63;
    const int l16  = lane & 15;
    const int quad = lane >> 4;
    const int b    = bh >> 4, h = bh & 15;

    // Q fragments: two 16-row halves of this wave's 32 rows
    shortx8 aq[2][2];
#pragma unroll
    for (int mh = 0; mh < 2; ++mh) {
        const __hip_bfloat16* qbase =
            qh + ((size_t)bh * S_ + q0 + wv * 32 + mh * 16 + l16) * HD_;
        aq[mh][0] = *(const shortx8*)(qbase + quad * 8);
        aq[mh][1] = *(const shortx8*)(qbase + 32 + quad * 8);
    }

    const halfx8 ones = {(_Float16)1.f, (_Float16)1.f, (_Float16)1.f, (_Float16)1.f,
                         (_Float16)1.f, (_Float16)1.f, (_Float16)1.f, (_Float16)1.f};

    floatx4 O[2][4] = {};     // O^T accumulators [m-half][d-tile]
    floatx4 O5[2]   = {};     // l accumulators (all regs equal)

    const __hip_bfloat16* __restrict__ kbase = kh + (size_t)bh * S_ * HD_;
    const _Float16* __restrict__ vbase = vt + (size_t)bh * HD_ * S_;

    const int sr = tid >> 1, sc = (tid & 1) * 32;   // K staging: 128 rows x 64
    const int vr = tid >> 2, vc = (tid & 3) * 32;   // V staging: 64 rows x 128

    for (int kt = 0; kt < S_ / 128; ++kt) {
        {
            const __hip_bfloat16* kp = kbase + ((size_t)(kt * 128 + sr)) * HD_ + sc;
            uint4 k0 = ((const uint4*)kp)[0];
            uint4 k1 = ((const uint4*)kp)[1];
            uint4 k2 = ((const uint4*)kp)[2];
            uint4 k3 = ((const uint4*)kp)[3];
            *(uint4*)&Kt[sr][sc]      = k0;
            *(uint4*)&Kt[sr][sc + 8]  = k1;
            *(uint4*)&Kt[sr][sc + 16] = k2;
            *(uint4*)&Kt[sr][sc + 24] = k3;
            const _Float16* vp = vbase + (size_t)vr * S_ + kt * 128 + vc;
            uint4 v0 = ((const uint4*)vp)[0];
            uint4 v1 = ((const uint4*)vp)[1];
            uint4 v2 = ((const uint4*)vp)[2];
            uint4 v3 = ((const uint4*)vp)[3];
            *(uint4*)&Vt[vr][vc]      = v0;
            *(uint4*)&Vt[vr][vc + 8]  = v1;
            *(uint4*)&Vt[vr][vc + 16] = v2;
            *(uint4*)&Vt[vr][vc + 24] = v3;
        }
        __syncthreads();

#pragma unroll
        for (int hk = 0; hk < 2; ++hk) {          // two 64-key halves
            // ---- S^T = K * Q^T, K frags shared across both mh ----
            floatx4 s4[2][4];
#pragma unroll
            for (int nt = 0; nt < 4; ++nt) {
                const shortx8 kb0 =
                    *(const shortx8*)&Kt[hk * 64 + nt * 16 + l16][quad * 8];
                const shortx8 kb1 =
                    *(const shortx8*)&Kt[hk * 64 + nt * 16 + l16][32 + quad * 8];
#pragma unroll
                for (int mh = 0; mh < 2; ++mh) {
                    floatx4 c = {0.f, 0.f, 0.f, 0.f};
                    c = __builtin_amdgcn_mfma_f32_16x16x32_bf16(kb0, aq[mh][0], c, 0, 0, 0);
                    c = __builtin_amdgcn_mfma_f32_16x16x32_bf16(kb1, aq[mh][1], c, 0, 0, 0);
                    s4[mh][nt] = c;
                }
            }

            // ---- P^T = exp2(S^T), packed to K=32 f16 B-frags ----
            halfx8 bb[2][2];
#pragma unroll
            for (int mh = 0; mh < 2; ++mh)
#pragma unroll
                for (int f = 0; f < 2; ++f) {
                    halfx8 hb;
#pragma unroll
                    for (int r = 0; r < 4; ++r)
                        hb[r] = (_Float16)exp2f(s4[mh][2 * f][r]);
#pragma unroll
                    for (int r = 0; r < 4; ++r)
                        hb[4 + r] = (_Float16)exp2f(s4[mh][2 * f + 1][r]);
                    bb[mh][f] = hb;
                }

            // ---- l += ones * P^T (MFMA; no LDS, no shuffles) ----
#pragma unroll
            for (int mh = 0; mh < 2; ++mh) {
                O5[mh] = __builtin_amdgcn_mfma_f32_16x16x32_f16(ones, bb[mh][0], O5[mh], 0, 0, 0);
                O5[mh] = __builtin_amdgcn_mfma_f32_16x16x32_f16(ones, bb[mh][1], O5[mh], 0, 0, 0);
            }

            // ---- O^T += V^T * P^T, V frags shared across both mh ----
#pragma unroll
            for (int dt = 0; dt < 4; ++dt) {
                const _Float16* vrow = &Vt[dt * 16 + l16][hk * 64];
                const halfx4 a0 = *(const halfx4*)(vrow + quad * 4);
                const halfx4 a1 = *(const halfx4*)(vrow + 16 + quad * 4);
                const halfx4 a2 = *(const halfx4*)(vrow + 32 + quad * 4);
                const halfx4 a3 = *(const halfx4*)(vrow + 48 + quad * 4);
                const halfx8 A0 = __builtin_shufflevector(a0, a1, 0, 1, 2, 3, 4, 5, 6, 7);
                const halfx8 A1 = __builtin_shufflevector(a2, a3, 0, 1, 2, 3, 4, 5, 6, 7);
#pragma unroll
                for (int mh = 0; mh < 2; ++mh) {
                    O[mh][dt] = __builtin_amdgcn_mfma_f32_16x16x32_f16(
                        A0, bb[mh][0], O[mh][dt], 0, 0, 0);
                    O[mh][dt] = __builtin_amdgcn_mfma_f32_16x16x32_f16(
                        A1, bb[mh][1], O[mh][dt], 0, 0, 0);
                }
            }
        }
        __syncthreads();
    }

    // ---- epilogue: normalize (l = O5[mh][0], per-lane), 8B stores ----
#pragma unroll
    for (int mh = 0; mh < 2; ++mh) {
        const float inv = 1.0f / O5[mh][0];
        const int s = q0 + wv * 32 + mh * 16 + l16;       // q = l16
        __hip_bfloat16* cb = ctx + ((size_t)(b * S_ + s)) * E_ + h * HD_;
#pragma unroll
        for (int dt = 0; dt < 4; ++dt) {
            __hip_bfloat16 pk[4];
#pragma unroll
            for (int r = 0; r < 4; ++r)
                pk[r] = __float2bfloat16(O[mh][dt][r] * inv);
            *(ushort4*)(cb + dt * 16 + quad * 4) = *(const ushort4*)pk;
        }
    }
}

// ---------------------------------------------------------------------------
// Kernel 3: out[m][n] = sum_k ctx[m][k] * W[n][k] + bias[n], fp32 out.
// 128x128 tile, BK=32, LDS stride 40 (2-way banks, free). XCD-swizzled 1D
// grid: each XCD owns 8 m-blocks (ctx-local) x all 8 n-blocks.
// ---------------------------------------------------------------------------
__global__ __launch_bounds__(256) void proj(
    const __hip_bfloat16* __restrict__ ctx, const __hip_bfloat16* __restrict__ wb,
    const float* __restrict__ bias, float* __restrict__ out)
{
    __shared__ __hip_bfloat16 As[128][40];   // [m][k] 10 KB
    __shared__ __hip_bfloat16 Bs[128][40];   // [n][k] 10 KB

    const int bid  = blockIdx.x;
    const int slot = bid >> 3;
    const int mblk = ((bid & 7) << 3) | (slot & 7);   // 0..63
    const int nblk = slot >> 3;                        // 0..7
    const int m0 = mblk * 128;
    const int n0 = nblk * 128;
    const int tid  = threadIdx.x;
    const int wv   = tid >> 6;
    const int lane = tid & 63;
    const int l16  = lane & 15;
    const int quad = lane >> 4;
    const int wr   = (wv >> 1) * 64;
    const int wc   = (wv & 1) * 64;

    const int srow = tid >> 1;
    const int scol = (tid & 1) * 16;

    floatx4 acc[4][4] = {};

    for (int k0 = 0; k0 < E_; k0 += 32) {
        const uint4* ap = (const uint4*)(ctx + (size_t)(m0 + srow) * E_ + k0 + scol);
        const uint4* bp = (const uint4*)(wb  + (size_t)(n0 + srow) * E_ + k0 + scol);
        uint4 a0 = ap[0], a1 = ap[1];
        uint4 b0 = bp[0], b1 = bp[1];
        *(uint4*)&As[srow][scol]     = a0;
        *(uint4*)&As[srow][scol + 8] = a1;
        *(uint4*)&Bs[srow][scol]     = b0;
        *(uint4*)&Bs[srow][scol + 8] = b1;
        __syncthreads();

        shortx8 af[4], bf[4];
#pragma unroll
        for (int mt = 0; mt < 4; ++mt)
            af[mt] = *(const shortx8*)&As[wr + mt * 16 + l16][quad * 8];
#pragma unroll
        for (int nt = 0; nt < 4; ++nt)
            bf[nt] = *(const shortx8*)&Bs[wc + nt * 16 + l16][quad * 8];

#pragma unroll
        for (int mt = 0; mt < 4; ++mt)
#pragma unroll
            for (int nt = 0; nt < 4; ++nt)
                acc[mt][nt] = __builtin_amdgcn_mfma_f32_16x16x32_bf16(
                    af[mt], bf[nt], acc[mt][nt], 0, 0, 0);
        __syncthreads();
    }

#pragma unroll
    for (int nt = 0; nt < 4; ++nt) {
        const float bv = bias[n0 + wc + nt * 16 + l16];
#pragma unroll
        for (int mt = 0; mt < 4; ++mt)
#pragma unroll
            for (int r = 0; r < 4; ++r) {
                const int mrow = m0 + wr + mt * 16 + quad * 4 + r;
                const int ncol = n0 + wc + nt * 16 + l16;
                out[(size_t)mrow * E_ + ncol] = acc[mt][nt][r] + bv;
            }
    }
}

// ---------------------------------------------------------------------------
extern "C" void kernel_launch(void* const* d_in, const int* in_sizes, int n_in,
                              void* d_out, int out_size, void* d_ws, size_t ws_size,
                              hipStream_t stream)
{
    const float* q  = (const float*)d_in[0];
    const float* k  = (const float*)d_in[1];
    const float* v  = (const float*)d_in[2];
    const float* qw = (const float*)d_in[3];
    const float* kw = (const float*)d_in[4];
    const float* pw = (const float*)d_in[5];
    const float* pb = (const float*)d_in[6];
    float* out = (float*)d_out;

    char* ws = (char*)d_ws;
    const size_t SEG = (size_t)B_ * H_ * S_ * HD_ * 2;   // 16 MiB
    __hip_bfloat16* qh  = (__hip_bfloat16*)(ws);
    __hip_bfloat16* kh  = (__hip_bfloat16*)(ws + SEG);
    _Float16*       vt  = (_Float16*)(ws + 2 * SEG);
    __hip_bfloat16* ctx = (__hip_bfloat16*)(ws + 3 * SEG);
    __hip_bfloat16* wbp = (__hip_bfloat16*)(ws + 4 * SEG);

    prep<<<dim3(19456), 256, 0, stream>>>(q, k, v, qw, kw, pw, qh, kh, vt, wbp);
    attn<<<dim3(1024), 256, 0, stream>>>(qh, kh, vt, ctx);
    proj<<<dim3(512), 256, 0, stream>>>(ctx, wbp, pb, out);
}

// Round 9
// 252.773 us; speedup vs baseline: 1.3434x; 1.1073x over previous
//
#include <hip/hip_runtime.h>
#include <hip/hip_bf16.h>
#include <cstdint>

#define B_ 4
#define S_ 2048
#define E_ 1024
#define H_ 16
#define HD_ 64
#define EPS_ 1.1920928955078125e-07f

typedef __attribute__((ext_vector_type(8))) short shortx8;
typedef __attribute__((ext_vector_type(4))) float floatx4;
typedef __attribute__((ext_vector_type(4))) _Float16 halfx4;
typedef __attribute__((ext_vector_type(8))) _Float16 halfx8;
typedef __attribute__((ext_vector_type(2))) __fp16 fp16x2;

// softmax scale folded into Q at prep time: Q *= 0.125*log2(e), so
// P = exp2(QK^T) directly. |logit*0.125| <= 8 (Cauchy-Schwarz after RMSNorm)
// so p <= e^8 ~ 2981 -- in fp16 range; normalization divides it out.
#define C1_ 0.18033688068389154f   // 0.125 * log2(e)

// ---------------------------------------------------------------------------
// Kernel 1 (fused prep): three block-uniform jobs in one dispatch.
//   bid <  16384 : RMSNorm+RoPE q,k -> bf16 [B,H,S,HD] (Q pre-scaled C1_)
//   bid <  18432 : V transpose -> fp16 [B,H,HD,S], keys PERMUTED within each
//                  64-group: n = (o&32) + ((o&15)>>2)*8 + ((o>>4)&1)*4, so
//                  attn's PV A-frag is two contiguous b128 LDS reads.
//   else         : proj_w fp32 -> bf16
// ---------------------------------------------------------------------------
__global__ __launch_bounds__(256) void prep(
    const float* __restrict__ q, const float* __restrict__ k,
    const float* __restrict__ v,
    const float* __restrict__ qw, const float* __restrict__ kw,
    const float* __restrict__ pw,
    __hip_bfloat16* __restrict__ qh, __hip_bfloat16* __restrict__ kh,
    _Float16* __restrict__ vt, __hip_bfloat16* __restrict__ wb)
{
    __shared__ _Float16 tile[64][72];
    const int bid = blockIdx.x;
    const int tid = threadIdx.x;

    if (bid < 16384) {
        // ---- RMSNorm + RoPE ----
        const size_t PT = (size_t)B_ * S_ * E_ / 4;
        size_t t = (size_t)bid * 256 + tid;
        const bool is_k = (t >= PT);
        if (is_k) t -= PT;

        const int row = (int)(t >> 8);
        const int b   = row / S_;
        const int s   = row % S_;
        const int grp = (int)(t & 255);
        const int h   = grp >> 4;
        const int dl  = (grp & 15) * 4;

        const float* __restrict__ src = is_k ? k : q;
        const float* __restrict__ w   = is_k ? kw : qw;
        __hip_bfloat16* __restrict__ dst = is_k ? kh : qh;

        const float4 x  = ((const float4*)src)[t];
        const float4 wv = ((const float4*)w)[grp & 15];

        float ss = x.x * x.x + x.y * x.y + x.z * x.z + x.w * x.w;
#pragma unroll
        for (int m = 1; m < 16; m <<= 1) ss += __shfl_xor(ss, m);
        float r = rsqrtf(ss * (1.0f / HD_) + EPS_);
        if (!is_k) r *= C1_;

        const float xn0 = x.x * r * wv.x;
        const float xn1 = x.y * r * wv.y;
        const float xn2 = x.z * r * wv.z;
        const float xn3 = x.w * r * wv.w;

        const float L2I = 0.41524101186092029f;   // log2(10000)/32
        const int   i0  = dl >> 1;
        const float f0  = (float)s * __builtin_amdgcn_exp2f(-(float)i0 * L2I);
        const float f1  = (float)s * __builtin_amdgcn_exp2f(-(float)(i0 + 1) * L2I);
        const float c0 = __cosf(f0), sn0 = __sinf(f0);
        const float c1 = __cosf(f1), sn1 = __sinf(f1);

        __hip_bfloat16 pk[4];
        pk[0] = __float2bfloat16(xn0 * c0 - xn1 * sn0);
        pk[1] = __float2bfloat16(xn0 * sn0 + xn1 * c0);
        pk[2] = __float2bfloat16(xn2 * c1 - xn3 * sn1);
        pk[3] = __float2bfloat16(xn2 * sn1 + xn3 * c1);
        *(ushort4*)(dst + ((size_t)((b * H_ + h) * S_ + s)) * HD_ + dl) =
            *(const ushort4*)pk;
    } else if (bid < 18432) {
        // ---- V transpose + key permutation ----
        const int bb2 = bid - 16384;
        const int s0  = (bb2 & 31) * 64;          // one 64-key group
        const int bh  = bb2 >> 5;
        const int b   = bh >> 4, h = bh & 15;
        {
            const int sl = tid >> 2;
            const int d0 = (tid & 3) * 16;
            const float* __restrict__ src =
                v + ((size_t)(b * S_ + s0 + sl)) * E_ + h * HD_ + d0;
            float4 f0 = ((const float4*)src)[0];
            float4 f1 = ((const float4*)src)[1];
            float4 f2 = ((const float4*)src)[2];
            float4 f3 = ((const float4*)src)[3];
            float vals[16] = {f0.x,f0.y,f0.z,f0.w, f1.x,f1.y,f1.z,f1.w,
                              f2.x,f2.y,f2.z,f2.w, f3.x,f3.y,f3.z,f3.w};
#pragma unroll
            for (int j = 0; j < 16; ++j)
                tile[d0 + j][sl] = (_Float16)vals[j];
        }
        __syncthreads();
        {
            const int d  = tid >> 2;
            const int sg = (tid & 3) * 16;
            _Float16* __restrict__ dstrow =
                vt + ((size_t)(bh * HD_ + d)) * S_ + s0;
#pragma unroll
            for (int g = 0; g < 4; ++g) {
                const int o = sg + 4 * g;
                const int n = (o & 32) + (((o & 15) >> 2) << 3) + (((o >> 4) & 1) << 2);
                *(ushort4*)(dstrow + n) = *(const ushort4*)&tile[d][o];
            }
        }
    } else {
        // ---- W conv ----
        const int i = (bid - 18432) * 256 + tid;
        float4 f = ((const float4*)pw)[i];
        wb[4 * i + 0] = __float2bfloat16(f.x);
        wb[4 * i + 1] = __float2bfloat16(f.y);
        wb[4 * i + 2] = __float2bfloat16(f.z);
        wb[4 * i + 3] = __float2bfloat16(f.w);
    }
}

// ---------------------------------------------------------------------------
// Kernel 2: flash attention. S^T trick + K=32 f16 PV (key permutation baked
// into vt layout), frags shared across both 16-q halves, l via ones-MFMA,
// XCD-swizzled 1D grid.
//   S^T = K*Q^T (mfma 16x16x32 bf16, A=K B=Q): C[key=quad*4+r][q=l16].
//   PV B-frag slot (quad,j): j<4 <- s4[2f] (key quad*4+j), j>=4 <- s4[2f+1];
//   vt's permuted layout makes the matching A-frag = b128 at col quad*8
//   (+32 for f=1) within each 64-key group.
// ---------------------------------------------------------------------------
__global__ __launch_bounds__(256, 4) void attn(
    const __hip_bfloat16* __restrict__ qh, const __hip_bfloat16* __restrict__ kh,
    const _Float16* __restrict__ vt, __hip_bfloat16* __restrict__ ctx)
{
    __shared__ __hip_bfloat16 Kt[128][72];   // [key][d]   18.4 KB
    __shared__ _Float16       Vt[64][152];   // [d][key]   19.0 KB

    const int bid  = blockIdx.x;
    const int slot = bid >> 3;
    const int bh   = ((bid & 7) << 3) | (slot & 7);   // XCD-local bh
    const int q0   = (slot >> 3) * 128;
    const int tid  = threadIdx.x;
    const int wv   = tid >> 6;
    const int lane = tid & 63;
    const int l16  = lane & 15;
    const int quad = lane >> 4;
    const int b    = bh >> 4, h = bh & 15;

    // Q fragments: two 16-row halves of this wave's 32 rows
    shortx8 aq[2][2];
#pragma unroll
    for (int mh = 0; mh < 2; ++mh) {
        const __hip_bfloat16* qbase =
            qh + ((size_t)bh * S_ + q0 + wv * 32 + mh * 16 + l16) * HD_;
        aq[mh][0] = *(const shortx8*)(qbase + quad * 8);
        aq[mh][1] = *(const shortx8*)(qbase + 32 + quad * 8);
    }

    const halfx8 ones = {(_Float16)1.f, (_Float16)1.f, (_Float16)1.f, (_Float16)1.f,
                         (_Float16)1.f, (_Float16)1.f, (_Float16)1.f, (_Float16)1.f};

    floatx4 O[2][4] = {};     // O^T accumulators [m-half][d-tile]
    floatx4 O5[2]   = {};     // l accumulators

    const __hip_bfloat16* __restrict__ kbase = kh + (size_t)bh * S_ * HD_;
    const _Float16* __restrict__ vbase = vt + (size_t)bh * HD_ * S_;

    const int sr = tid >> 1, sc = (tid & 1) * 32;   // K staging: 128 rows x 64
    const int vr = tid >> 2, vc = (tid & 3) * 32;   // V staging: 64 rows x 128

    for (int kt = 0; kt < S_ / 128; ++kt) {
        {
            const __hip_bfloat16* kp = kbase + ((size_t)(kt * 128 + sr)) * HD_ + sc;
            uint4 k0 = ((const uint4*)kp)[0];
            uint4 k1 = ((const uint4*)kp)[1];
            uint4 k2 = ((const uint4*)kp)[2];
            uint4 k3 = ((const uint4*)kp)[3];
            *(uint4*)&Kt[sr][sc]      = k0;
            *(uint4*)&Kt[sr][sc + 8]  = k1;
            *(uint4*)&Kt[sr][sc + 16] = k2;
            *(uint4*)&Kt[sr][sc + 24] = k3;
            const _Float16* vp = vbase + (size_t)vr * S_ + kt * 128 + vc;
            uint4 v0 = ((const uint4*)vp)[0];
            uint4 v1 = ((const uint4*)vp)[1];
            uint4 v2 = ((const uint4*)vp)[2];
            uint4 v3 = ((const uint4*)vp)[3];
            *(uint4*)&Vt[vr][vc]      = v0;
            *(uint4*)&Vt[vr][vc + 8]  = v1;
            *(uint4*)&Vt[vr][vc + 16] = v2;
            *(uint4*)&Vt[vr][vc + 24] = v3;
        }
        __syncthreads();

#pragma unroll
        for (int hk = 0; hk < 2; ++hk) {          // two 64-key halves
            // ---- S^T = K * Q^T, K frags shared across both mh ----
            floatx4 s4[2][4];
#pragma unroll
            for (int nt = 0; nt < 4; ++nt) {
                const shortx8 kb0 =
                    *(const shortx8*)&Kt[hk * 64 + nt * 16 + l16][quad * 8];
                const shortx8 kb1 =
                    *(const shortx8*)&Kt[hk * 64 + nt * 16 + l16][32 + quad * 8];
#pragma unroll
                for (int mh = 0; mh < 2; ++mh) {
                    floatx4 c = {0.f, 0.f, 0.f, 0.f};
                    c = __builtin_amdgcn_mfma_f32_16x16x32_bf16(kb0, aq[mh][0], c, 0, 0, 0);
                    c = __builtin_amdgcn_mfma_f32_16x16x32_bf16(kb1, aq[mh][1], c, 0, 0, 0);
                    s4[mh][nt] = c;
                }
            }

            // ---- P^T = exp2(S^T) via native exp + packed cvt ----
            halfx8 bb[2][2];
#pragma unroll
            for (int mh = 0; mh < 2; ++mh)
#pragma unroll
                for (int f = 0; f < 2; ++f) {
                    union { fp16x2 h2[4]; halfx8 h8; } u;
                    u.h2[0] = __builtin_amdgcn_cvt_pkrtz(
                        __builtin_amdgcn_exp2f(s4[mh][2 * f][0]),
                        __builtin_amdgcn_exp2f(s4[mh][2 * f][1]));
                    u.h2[1] = __builtin_amdgcn_cvt_pkrtz(
                        __builtin_amdgcn_exp2f(s4[mh][2 * f][2]),
                        __builtin_amdgcn_exp2f(s4[mh][2 * f][3]));
                    u.h2[2] = __builtin_amdgcn_cvt_pkrtz(
                        __builtin_amdgcn_exp2f(s4[mh][2 * f + 1][0]),
                        __builtin_amdgcn_exp2f(s4[mh][2 * f + 1][1]));
                    u.h2[3] = __builtin_amdgcn_cvt_pkrtz(
                        __builtin_amdgcn_exp2f(s4[mh][2 * f + 1][2]),
                        __builtin_amdgcn_exp2f(s4[mh][2 * f + 1][3]));
                    bb[mh][f] = u.h8;
                }

            // ---- l += ones * P^T ----
#pragma unroll
            for (int mh = 0; mh < 2; ++mh) {
                O5[mh] = __builtin_amdgcn_mfma_f32_16x16x32_f16(ones, bb[mh][0], O5[mh], 0, 0, 0);
                O5[mh] = __builtin_amdgcn_mfma_f32_16x16x32_f16(ones, bb[mh][1], O5[mh], 0, 0, 0);
            }

            // ---- O^T += V^T * P^T; A-frags are direct b128 reads ----
#pragma unroll
            for (int dt = 0; dt < 4; ++dt) {
                const _Float16* vrow = &Vt[dt * 16 + l16][hk * 64];
                const halfx8 A0 = *(const halfx8*)(vrow + quad * 8);
                const halfx8 A1 = *(const halfx8*)(vrow + 32 + quad * 8);
#pragma unroll
                for (int mh = 0; mh < 2; ++mh) {
                    O[mh][dt] = __builtin_amdgcn_mfma_f32_16x16x32_f16(
                        A0, bb[mh][0], O[mh][dt], 0, 0, 0);
                    O[mh][dt] = __builtin_amdgcn_mfma_f32_16x16x32_f16(
                        A1, bb[mh][1], O[mh][dt], 0, 0, 0);
                }
            }
        }
        __syncthreads();
    }

    // ---- epilogue: normalize (l = O5[mh][0], per-lane), 8B stores ----
#pragma unroll
    for (int mh = 0; mh < 2; ++mh) {
        const float inv = 1.0f / O5[mh][0];
        const int s = q0 + wv * 32 + mh * 16 + l16;       // q = l16
        __hip_bfloat16* cb = ctx + ((size_t)(b * S_ + s)) * E_ + h * HD_;
#pragma unroll
        for (int dt = 0; dt < 4; ++dt) {
            __hip_bfloat16 pk[4];
#pragma unroll
            for (int r = 0; r < 4; ++r)
                pk[r] = __float2bfloat16(O[mh][dt][r] * inv);
            *(ushort4*)(cb + dt * 16 + quad * 4) = *(const ushort4*)pk;
        }
    }
}

// ---------------------------------------------------------------------------
// Kernel 3: out[m][n] = sum_k ctx[m][k] * W[n][k] + bias[n], fp32 out.
// 128x128 tile, BK=64 (32 MFMA between barriers), LDS stride 72 bf16 (144B).
// XCD-swizzled 1D grid.
// ---------------------------------------------------------------------------
__global__ __launch_bounds__(256) void proj(
    const __hip_bfloat16* __restrict__ ctx, const __hip_bfloat16* __restrict__ wb,
    const float* __restrict__ bias, float* __restrict__ out)
{
    __shared__ __hip_bfloat16 As[128][72];   // [m][k] 18.4 KB
    __shared__ __hip_bfloat16 Bs[128][72];   // [n][k] 18.4 KB

    const int bid  = blockIdx.x;
    const int slot = bid >> 3;
    const int mblk = ((bid & 7) << 3) | (slot & 7);   // 0..63
    const int nblk = slot >> 3;                        // 0..7
    const int m0 = mblk * 128;
    const int n0 = nblk * 128;
    const int tid  = threadIdx.x;
    const int wv   = tid >> 6;
    const int lane = tid & 63;
    const int l16  = lane & 15;
    const int quad = lane >> 4;
    const int wr   = (wv >> 1) * 64;
    const int wc   = (wv & 1) * 64;

    const int srow = tid >> 1;
    const int scol = (tid & 1) * 32;

    floatx4 acc[4][4] = {};

    for (int k0 = 0; k0 < E_; k0 += 64) {
        const uint4* ap = (const uint4*)(ctx + (size_t)(m0 + srow) * E_ + k0 + scol);
        const uint4* bp = (const uint4*)(wb  + (size_t)(n0 + srow) * E_ + k0 + scol);
        uint4 a0 = ap[0], a1 = ap[1], a2 = ap[2], a3 = ap[3];
        uint4 b0 = bp[0], b1 = bp[1], b2 = bp[2], b3 = bp[3];
        *(uint4*)&As[srow][scol]      = a0;
        *(uint4*)&As[srow][scol + 8]  = a1;
        *(uint4*)&As[srow][scol + 16] = a2;
        *(uint4*)&As[srow][scol + 24] = a3;
        *(uint4*)&Bs[srow][scol]      = b0;
        *(uint4*)&Bs[srow][scol + 8]  = b1;
        *(uint4*)&Bs[srow][scol + 16] = b2;
        *(uint4*)&Bs[srow][scol + 24] = b3;
        __syncthreads();

#pragma unroll
        for (int ks = 0; ks < 2; ++ks) {
            shortx8 af[4], bf[4];
#pragma unroll
            for (int mt = 0; mt < 4; ++mt)
                af[mt] = *(const shortx8*)&As[wr + mt * 16 + l16][ks * 32 + quad * 8];
#pragma unroll
            for (int nt = 0; nt < 4; ++nt)
                bf[nt] = *(const shortx8*)&Bs[wc + nt * 16 + l16][ks * 32 + quad * 8];

#pragma unroll
            for (int mt = 0; mt < 4; ++mt)
#pragma unroll
                for (int nt = 0; nt < 4; ++nt)
                    acc[mt][nt] = __builtin_amdgcn_mfma_f32_16x16x32_bf16(
                        af[mt], bf[nt], acc[mt][nt], 0, 0, 0);
        }
        __syncthreads();
    }

#pragma unroll
    for (int nt = 0; nt < 4; ++nt) {
        const float bv = bias[n0 + wc + nt * 16 + l16];
#pragma unroll
        for (int mt = 0; mt < 4; ++mt)
#pragma unroll
            for (int r = 0; r < 4; ++r) {
                const int mrow = m0 + wr + mt * 16 + quad * 4 + r;
                const int ncol = n0 + wc + nt * 16 + l16;
                out[(size_t)mrow * E_ + ncol] = acc[mt][nt][r] + bv;
            }
    }
}

// ---------------------------------------------------------------------------
extern "C" void kernel_launch(void* const* d_in, const int* in_sizes, int n_in,
                              void* d_out, int out_size, void* d_ws, size_t ws_size,
                              hipStream_t stream)
{
    const float* q  = (const float*)d_in[0];
    const float* k  = (const float*)d_in[1];
    const float* v  = (const float*)d_in[2];
    const float* qw = (const float*)d_in[3];
    const float* kw = (const float*)d_in[4];
    const float* pw = (const float*)d_in[5];
    const float* pb = (const float*)d_in[6];
    float* out = (float*)d_out;

    char* ws = (char*)d_ws;
    const size_t SEG = (size_t)B_ * H_ * S_ * HD_ * 2;   // 16 MiB
    __hip_bfloat16* qh  = (__hip_bfloat16*)(ws);
    __hip_bfloat16* kh  = (__hip_bfloat16*)(ws + SEG);
    _Float16*       vt  = (_Float16*)(ws + 2 * SEG);
    __hip_bfloat16* ctx = (__hip_bfloat16*)(ws + 3 * SEG);
    __hip_bfloat16* wbp = (__hip_bfloat16*)(ws + 4 * SEG);

    prep<<<dim3(19456), 256, 0, stream>>>(q, k, v, qw, kw, pw, qh, kh, vt, wbp);
    attn<<<dim3(1024), 256, 0, stream>>>(qh, kh, vt, ctx);
    proj<<<dim3(512), 256, 0, stream>>>(ctx, wbp, pb, out);
}

// Round 10
// 249.726 us; speedup vs baseline: 1.3598x; 1.0122x over previous
//
#include <hip/hip_runtime.h>
#include <hip/hip_bf16.h>
#include <cstdint>

#define B_ 4
#define S_ 2048
#define E_ 1024
#define H_ 16
#define HD_ 64
#define EPS_ 1.1920928955078125e-07f

typedef __attribute__((ext_vector_type(8))) short shortx8;
typedef __attribute__((ext_vector_type(4))) float floatx4;
typedef __attribute__((ext_vector_type(8))) _Float16 halfx8;
typedef __attribute__((ext_vector_type(2))) __fp16 fp16x2;

// softmax scale folded into Q at prep time: Q *= 0.125*log2(e), so
// P = exp2(QK^T) directly. |logit*0.125| <= 8 (Cauchy-Schwarz after RMSNorm)
// so p <= e^8 ~ 2981 -- in fp16 range; normalization divides it out.
#define C1_ 0.18033688068389154f   // 0.125 * log2(e)

// ---------------------------------------------------------------------------
// Kernel 1 (fused prep): three block-uniform jobs in one dispatch.
//   bid <  16384 : RMSNorm+RoPE q,k -> bf16 [B,H,S,HD] (Q pre-scaled C1_)
//   bid <  18432 : V transpose -> fp16 [B,H,HD,S], keys PERMUTED within each
//                  64-group (perm applied INSIDE the LDS tile so global
//                  stores stay contiguous 16B):
//                  n = (o&32) | ((o>>2)&3)<<3 | ((o>>4)&1)<<2 | (o&3)
//   else         : proj_w fp32 -> bf16
// ---------------------------------------------------------------------------
__global__ __launch_bounds__(256) void prep(
    const float* __restrict__ q, const float* __restrict__ k,
    const float* __restrict__ v,
    const float* __restrict__ qw, const float* __restrict__ kw,
    const float* __restrict__ pw,
    __hip_bfloat16* __restrict__ qh, __hip_bfloat16* __restrict__ kh,
    _Float16* __restrict__ vt, __hip_bfloat16* __restrict__ wb)
{
    __shared__ _Float16 tile[64][72];
    const int bid = blockIdx.x;
    const int tid = threadIdx.x;

    if (bid < 16384) {
        // ---- RMSNorm + RoPE ----
        const size_t PT = (size_t)B_ * S_ * E_ / 4;
        size_t t = (size_t)bid * 256 + tid;
        const bool is_k = (t >= PT);
        if (is_k) t -= PT;

        const int row = (int)(t >> 8);
        const int b   = row / S_;
        const int s   = row % S_;
        const int grp = (int)(t & 255);
        const int h   = grp >> 4;
        const int dl  = (grp & 15) * 4;

        const float* __restrict__ src = is_k ? k : q;
        const float* __restrict__ w   = is_k ? kw : qw;
        __hip_bfloat16* __restrict__ dst = is_k ? kh : qh;

        const float4 x  = ((const float4*)src)[t];
        const float4 wv = ((const float4*)w)[grp & 15];

        float ss = x.x * x.x + x.y * x.y + x.z * x.z + x.w * x.w;
#pragma unroll
        for (int m = 1; m < 16; m <<= 1) ss += __shfl_xor(ss, m);
        float r = rsqrtf(ss * (1.0f / HD_) + EPS_);
        if (!is_k) r *= C1_;

        const float xn0 = x.x * r * wv.x;
        const float xn1 = x.y * r * wv.y;
        const float xn2 = x.z * r * wv.z;
        const float xn3 = x.w * r * wv.w;

        const float L2I = 0.41524101186092029f;   // log2(10000)/32
        const int   i0  = dl >> 1;
        const float f0  = (float)s * __builtin_amdgcn_exp2f(-(float)i0 * L2I);
        const float f1  = (float)s * __builtin_amdgcn_exp2f(-(float)(i0 + 1) * L2I);
        const float c0 = __cosf(f0), sn0 = __sinf(f0);
        const float c1 = __cosf(f1), sn1 = __sinf(f1);

        __hip_bfloat16 pk[4];
        pk[0] = __float2bfloat16(xn0 * c0 - xn1 * sn0);
        pk[1] = __float2bfloat16(xn0 * sn0 + xn1 * c0);
        pk[2] = __float2bfloat16(xn2 * c1 - xn3 * sn1);
        pk[3] = __float2bfloat16(xn2 * sn1 + xn3 * c1);
        *(ushort4*)(dst + ((size_t)((b * H_ + h) * S_ + s)) * HD_ + dl) =
            *(const ushort4*)pk;
    } else if (bid < 18432) {
        // ---- V transpose; key permutation applied in the LDS tile ----
        const int bb2 = bid - 16384;
        const int s0  = (bb2 & 31) * 64;          // one 64-key group
        const int bh  = bb2 >> 5;
        const int b   = bh >> 4, h = bh & 15;
        {
            const int sl = tid >> 2;              // source key 0..63
            const int o  = sl;
            const int n  = (o & 32) | (((o >> 2) & 3) << 3) |
                           (((o >> 4) & 1) << 2) | (o & 3);
            const int d0 = (tid & 3) * 16;
            const float* __restrict__ src =
                v + ((size_t)(b * S_ + s0 + sl)) * E_ + h * HD_ + d0;
            float4 f0 = ((const float4*)src)[0];
            float4 f1 = ((const float4*)src)[1];
            float4 f2 = ((const float4*)src)[2];
            float4 f3 = ((const float4*)src)[3];
            float vals[16] = {f0.x,f0.y,f0.z,f0.w, f1.x,f1.y,f1.z,f1.w,
                              f2.x,f2.y,f2.z,f2.w, f3.x,f3.y,f3.z,f3.w};
#pragma unroll
            for (int j = 0; j < 16; ++j)
                tile[d0 + j][n] = (_Float16)vals[j];
        }
        __syncthreads();
        {
            const int d  = tid >> 2;
            const int sg = (tid & 3) * 16;
            _Float16* __restrict__ dst =
                vt + ((size_t)(bh * HD_ + d)) * S_ + s0 + sg;
            ((uint4*)dst)[0] = *(const uint4*)&tile[d][sg];
            ((uint4*)dst)[1] = *(const uint4*)&tile[d][sg + 8];
        }
    } else {
        // ---- W conv ----
        const int i = (bid - 18432) * 256 + tid;
        float4 f = ((const float4*)pw)[i];
        wb[4 * i + 0] = __float2bfloat16(f.x);
        wb[4 * i + 1] = __float2bfloat16(f.y);
        wb[4 * i + 2] = __float2bfloat16(f.z);
        wb[4 * i + 3] = __float2bfloat16(f.w);
    }
}

// ---------------------------------------------------------------------------
// Kernel 2: flash attention. S^T trick + K=32 f16 PV (key permutation baked
// into vt), 64 q-rows PER WAVE (BM=256/block) so K/V LDS-frag reads amortize
// over 4 m-halves -> LDS-pipe load drops below the MFMA floor. l via
// ones-MFMA. XCD-swizzled 1D grid (512 blocks, 2/CU).
//   S^T = K*Q^T (mfma 16x16x32 bf16, A=K B=Q): C[key=quad*4+r][q=l16].
//   PV B-frag slot (quad,j): j<4 <- s4[2f] (key quad*4+j), j>=4 <- s4[2f+1];
//   vt's permuted layout makes the matching A-frag = b128 at col quad*8
//   (+32 for f=1) within each 64-key group.
// ---------------------------------------------------------------------------
__global__ __launch_bounds__(256, 2) void attn(
    const __hip_bfloat16* __restrict__ qh, const __hip_bfloat16* __restrict__ kh,
    const _Float16* __restrict__ vt, __hip_bfloat16* __restrict__ ctx)
{
    __shared__ __hip_bfloat16 Kt[128][72];   // [key][d]   18.4 KB
    __shared__ _Float16       Vt[64][152];   // [d][key]   19.0 KB

    const int bid  = blockIdx.x;
    const int slot = bid >> 3;
    const int bh   = ((bid & 7) << 3) | (slot & 7);   // XCD-local bh
    const int q0   = (slot >> 3) * 256;
    const int tid  = threadIdx.x;
    const int wv   = tid >> 6;
    const int lane = tid & 63;
    const int l16  = lane & 15;
    const int quad = lane >> 4;
    const int b    = bh >> 4, h = bh & 15;

    // Q fragments: four 16-row m-halves of this wave's 64 rows
    shortx8 aq[4][2];
#pragma unroll
    for (int mh = 0; mh < 4; ++mh) {
        const __hip_bfloat16* qbase =
            qh + ((size_t)bh * S_ + q0 + wv * 64 + mh * 16 + l16) * HD_;
        aq[mh][0] = *(const shortx8*)(qbase + quad * 8);
        aq[mh][1] = *(const shortx8*)(qbase + 32 + quad * 8);
    }

    const halfx8 ones = {(_Float16)1.f, (_Float16)1.f, (_Float16)1.f, (_Float16)1.f,
                         (_Float16)1.f, (_Float16)1.f, (_Float16)1.f, (_Float16)1.f};

    floatx4 O[4][4] = {};     // O^T accumulators [m-half][d-tile]
    floatx4 O5[4]   = {};     // l accumulators

    const __hip_bfloat16* __restrict__ kbase = kh + (size_t)bh * S_ * HD_;
    const _Float16* __restrict__ vbase = vt + (size_t)bh * HD_ * S_;

    const int sr = tid >> 1, sc = (tid & 1) * 32;   // K staging: 128 rows x 64
    const int vr = tid >> 2, vc = (tid & 3) * 32;   // V staging: 64 rows x 128

    for (int kt = 0; kt < S_ / 128; ++kt) {
        {
            const __hip_bfloat16* kp = kbase + ((size_t)(kt * 128 + sr)) * HD_ + sc;
            uint4 k0 = ((const uint4*)kp)[0];
            uint4 k1 = ((const uint4*)kp)[1];
            uint4 k2 = ((const uint4*)kp)[2];
            uint4 k3 = ((const uint4*)kp)[3];
            *(uint4*)&Kt[sr][sc]      = k0;
            *(uint4*)&Kt[sr][sc + 8]  = k1;
            *(uint4*)&Kt[sr][sc + 16] = k2;
            *(uint4*)&Kt[sr][sc + 24] = k3;
            const _Float16* vp = vbase + (size_t)vr * S_ + kt * 128 + vc;
            uint4 v0 = ((const uint4*)vp)[0];
            uint4 v1 = ((const uint4*)vp)[1];
            uint4 v2 = ((const uint4*)vp)[2];
            uint4 v3 = ((const uint4*)vp)[3];
            *(uint4*)&Vt[vr][vc]      = v0;
            *(uint4*)&Vt[vr][vc + 8]  = v1;
            *(uint4*)&Vt[vr][vc + 16] = v2;
            *(uint4*)&Vt[vr][vc + 24] = v3;
        }
        __syncthreads();

#pragma unroll
        for (int hk = 0; hk < 2; ++hk) {          // two 64-key halves
            // ---- S^T = K * Q^T, K frags shared across all 4 mh ----
            floatx4 s4[4][4];
#pragma unroll
            for (int nt = 0; nt < 4; ++nt) {
                const shortx8 kb0 =
                    *(const shortx8*)&Kt[hk * 64 + nt * 16 + l16][quad * 8];
                const shortx8 kb1 =
                    *(const shortx8*)&Kt[hk * 64 + nt * 16 + l16][32 + quad * 8];
#pragma unroll
                for (int mh = 0; mh < 4; ++mh) {
                    floatx4 c = {0.f, 0.f, 0.f, 0.f};
                    c = __builtin_amdgcn_mfma_f32_16x16x32_bf16(kb0, aq[mh][0], c, 0, 0, 0);
                    c = __builtin_amdgcn_mfma_f32_16x16x32_bf16(kb1, aq[mh][1], c, 0, 0, 0);
                    s4[mh][nt] = c;
                }
            }

            // ---- P^T = exp2(S^T) via native exp + packed cvt ----
            halfx8 bb[4][2];
#pragma unroll
            for (int mh = 0; mh < 4; ++mh)
#pragma unroll
                for (int f = 0; f < 2; ++f) {
                    union { fp16x2 h2[4]; halfx8 h8; } u;
                    u.h2[0] = __builtin_amdgcn_cvt_pkrtz(
                        __builtin_amdgcn_exp2f(s4[mh][2 * f][0]),
                        __builtin_amdgcn_exp2f(s4[mh][2 * f][1]));
                    u.h2[1] = __builtin_amdgcn_cvt_pkrtz(
                        __builtin_amdgcn_exp2f(s4[mh][2 * f][2]),
                        __builtin_amdgcn_exp2f(s4[mh][2 * f][3]));
                    u.h2[2] = __builtin_amdgcn_cvt_pkrtz(
                        __builtin_amdgcn_exp2f(s4[mh][2 * f + 1][0]),
                        __builtin_amdgcn_exp2f(s4[mh][2 * f + 1][1]));
                    u.h2[3] = __builtin_amdgcn_cvt_pkrtz(
                        __builtin_amdgcn_exp2f(s4[mh][2 * f + 1][2]),
                        __builtin_amdgcn_exp2f(s4[mh][2 * f + 1][3]));
                    bb[mh][f] = u.h8;
                }

            // ---- l += ones * P^T ----
#pragma unroll
            for (int mh = 0; mh < 4; ++mh) {
                O5[mh] = __builtin_amdgcn_mfma_f32_16x16x32_f16(ones, bb[mh][0], O5[mh], 0, 0, 0);
                O5[mh] = __builtin_amdgcn_mfma_f32_16x16x32_f16(ones, bb[mh][1], O5[mh], 0, 0, 0);
            }

            // ---- O^T += V^T * P^T; V frags shared across all 4 mh ----
#pragma unroll
            for (int dt = 0; dt < 4; ++dt) {
                const _Float16* vrow = &Vt[dt * 16 + l16][hk * 64];
                const halfx8 A0 = *(const halfx8*)(vrow + quad * 8);
                const halfx8 A1 = *(const halfx8*)(vrow + 32 + quad * 8);
#pragma unroll
                for (int mh = 0; mh < 4; ++mh) {
                    O[mh][dt] = __builtin_amdgcn_mfma_f32_16x16x32_f16(
                        A0, bb[mh][0], O[mh][dt], 0, 0, 0);
                    O[mh][dt] = __builtin_amdgcn_mfma_f32_16x16x32_f16(
                        A1, bb[mh][1], O[mh][dt], 0, 0, 0);
                }
            }
        }
        __syncthreads();
    }

    // ---- epilogue: normalize (l = O5[mh][0], per-lane), 8B stores ----
#pragma unroll
    for (int mh = 0; mh < 4; ++mh) {
        const float inv = 1.0f / O5[mh][0];
        const int s = q0 + wv * 64 + mh * 16 + l16;       // q = l16
        __hip_bfloat16* cb = ctx + ((size_t)(b * S_ + s)) * E_ + h * HD_;
#pragma unroll
        for (int dt = 0; dt < 4; ++dt) {
            __hip_bfloat16 pk[4];
#pragma unroll
            for (int r = 0; r < 4; ++r)
                pk[r] = __float2bfloat16(O[mh][dt][r] * inv);
            *(ushort4*)(cb + dt * 16 + quad * 4) = *(const ushort4*)pk;
        }
    }
}

// ---------------------------------------------------------------------------
// Kernel 3: out[m][n] = sum_k ctx[m][k] * W[n][k] + bias[n], fp32 out.
// 128x128 tile, BK=64 (32 MFMA between barriers), LDS stride 72 bf16 (144B).
// XCD-swizzled 1D grid.
// ---------------------------------------------------------------------------
__global__ __launch_bounds__(256) void proj(
    const __hip_bfloat16* __restrict__ ctx, const __hip_bfloat16* __restrict__ wb,
    const float* __restrict__ bias, float* __restrict__ out)
{
    __shared__ __hip_bfloat16 As[128][72];   // [m][k] 18.4 KB
    __shared__ __hip_bfloat16 Bs[128][72];   // [n][k] 18.4 KB

    const int bid  = blockIdx.x;
    const int slot = bid >> 3;
    const int mblk = ((bid & 7) << 3) | (slot & 7);   // 0..63
    const int nblk = slot >> 3;                        // 0..7
    const int m0 = mblk * 128;
    const int n0 = nblk * 128;
    const int tid  = threadIdx.x;
    const int wv   = tid >> 6;
    const int lane = tid & 63;
    const int l16  = lane & 15;
    const int quad = lane >> 4;
    const int wr   = (wv >> 1) * 64;
    const int wc   = (wv & 1) * 64;

    const int srow = tid >> 1;
    const int scol = (tid & 1) * 32;

    floatx4 acc[4][4] = {};

    for (int k0 = 0; k0 < E_; k0 += 64) {
        const uint4* ap = (const uint4*)(ctx + (size_t)(m0 + srow) * E_ + k0 + scol);
        const uint4* bp = (const uint4*)(wb  + (size_t)(n0 + srow) * E_ + k0 + scol);
        uint4 a0 = ap[0], a1 = ap[1], a2 = ap[2], a3 = ap[3];
        uint4 b0 = bp[0], b1 = bp[1], b2 = bp[2], b3 = bp[3];
        *(uint4*)&As[srow][scol]      = a0;
        *(uint4*)&As[srow][scol + 8]  = a1;
        *(uint4*)&As[srow][scol + 16] = a2;
        *(uint4*)&As[srow][scol + 24] = a3;
        *(uint4*)&Bs[srow][scol]      = b0;
        *(uint4*)&Bs[srow][scol + 8]  = b1;
        *(uint4*)&Bs[srow][scol + 16] = b2;
        *(uint4*)&Bs[srow][scol + 24] = b3;
        __syncthreads();

#pragma unroll
        for (int ks = 0; ks < 2; ++ks) {
            shortx8 af[4], bf[4];
#pragma unroll
            for (int mt = 0; mt < 4; ++mt)
                af[mt] = *(const shortx8*)&As[wr + mt * 16 + l16][ks * 32 + quad * 8];
#pragma unroll
            for (int nt = 0; nt < 4; ++nt)
                bf[nt] = *(const shortx8*)&Bs[wc + nt * 16 + l16][ks * 32 + quad * 8];

#pragma unroll
            for (int mt = 0; mt < 4; ++mt)
#pragma unroll
                for (int nt = 0; nt < 4; ++nt)
                    acc[mt][nt] = __builtin_amdgcn_mfma_f32_16x16x32_bf16(
                        af[mt], bf[nt], acc[mt][nt], 0, 0, 0);
        }
        __syncthreads();
    }

#pragma unroll
    for (int nt = 0; nt < 4; ++nt) {
        const float bv = bias[n0 + wc + nt * 16 + l16];
#pragma unroll
        for (int mt = 0; mt < 4; ++mt)
#pragma unroll
            for (int r = 0; r < 4; ++r) {
                const int mrow = m0 + wr + mt * 16 + quad * 4 + r;
                const int ncol = n0 + wc + nt * 16 + l16;
                out[(size_t)mrow * E_ + ncol] = acc[mt][nt][r] + bv;
            }
    }
}

// ---------------------------------------------------------------------------
extern "C" void kernel_launch(void* const* d_in, const int* in_sizes, int n_in,
                              void* d_out, int out_size, void* d_ws, size_t ws_size,
                              hipStream_t stream)
{
    const float* q  = (const float*)d_in[0];
    const float* k  = (const float*)d_in[1];
    const float* v  = (const float*)d_in[2];
    const float* qw = (const float*)d_in[3];
    const float* kw = (const float*)d_in[4];
    const float* pw = (const float*)d_in[5];
    const float* pb = (const float*)d_in[6];
    float* out = (float*)d_out;

    char* ws = (char*)d_ws;
    const size_t SEG = (size_t)B_ * H_ * S_ * HD_ * 2;   // 16 MiB
    __hip_bfloat16* qh  = (__hip_bfloat16*)(ws);
    __hip_bfloat16* kh  = (__hip_bfloat16*)(ws + SEG);
    _Float16*       vt  = (_Float16*)(ws + 2 * SEG);
    __hip_bfloat16* ctx = (__hip_bfloat16*)(ws + 3 * SEG);
    __hip_bfloat16* wbp = (__hip_bfloat16*)(ws + 4 * SEG);

    prep<<<dim3(19456), 256, 0, stream>>>(q, k, v, qw, kw, pw, qh, kh, vt, wbp);
    attn<<<dim3(512), 256, 0, stream>>>(qh, kh, vt, ctx);
    proj<<<dim3(512), 256, 0, stream>>>(ctx, wbp, pb, out);
}